// Round 1
// baseline (196.263 us; speedup 1.0000x reference)
//
#include <hip/hip_runtime.h>
#include <hip/hip_bf16.h>

#define BATCH 4
#define CIN   256
#define CMID  128
#define NPOS  4096
#define EPS   1e-5f

typedef __bf16 bf16;
typedef __attribute__((ext_vector_type(8))) __bf16 bf16x8;
typedef __attribute__((ext_vector_type(4))) __bf16 bf16x4;
typedef __attribute__((ext_vector_type(4))) float  f32x4;

#define MFMA16(a, b, c) __builtin_amdgcn_mfma_f32_16x16x32_bf16((a), (b), (c), 0, 0, 0)

// XOR swizzle: 16B chunks within a row, chunk ^= (row & 7). Bijective, kills
// the 16-way bank conflict of row-major bf16 tiles read 16-rows-at-a-time.
__device__ __forceinline__ int swz128(int row, int colb) {
    return row * 128 + ((((colb >> 4) ^ (row & 7)) << 4) | (colb & 15));
}
__device__ __forceinline__ int swz256(int row, int colb) {
    return row * 256 + ((((colb >> 4) ^ (row & 7)) << 4) | (colb & 15));
}

// ---------------------------------------------------------------------------
// KT: x [B][CIN][N] f32  ->  xT [B][N][CIN] bf16   (LDS 64x64 tile transpose)
// ---------------------------------------------------------------------------
__global__ __launch_bounds__(256) void kt_transpose(const float* __restrict__ x,
                                                    bf16* __restrict__ xT) {
    __shared__ float tile[64][65];
    int n0 = blockIdx.x * 64, c0 = blockIdx.y * 64, b = blockIdx.z;
    const float* xp = x + (size_t)b * CIN * NPOS;
    int t = threadIdx.x;
    int lr = t >> 4;            // 0..15
    int lc4 = (t & 15) * 4;     // 0..60
    for (int p = 0; p < 4; ++p) {
        int c = lr + p * 16;
        f32x4 v = *reinterpret_cast<const f32x4*>(xp + (size_t)(c0 + c) * NPOS + n0 + lc4);
        tile[c][lc4 + 0] = v[0]; tile[c][lc4 + 1] = v[1];
        tile[c][lc4 + 2] = v[2]; tile[c][lc4 + 3] = v[3];
    }
    __syncthreads();
    bf16* xtp = xT + (size_t)b * NPOS * CIN;
    int cc = (t & 15) * 4;
    for (int p = 0; p < 4; ++p) {
        int n = (t >> 4) + p * 16;
        bf16x4 o;
        o[0] = (bf16)tile[cc + 0][n]; o[1] = (bf16)tile[cc + 1][n];
        o[2] = (bf16)tile[cc + 2][n]; o[3] = (bf16)tile[cc + 3][n];
        *reinterpret_cast<bf16x4*>(xtp + (size_t)(n0 + n) * CIN + c0 + cc) = o;
    }
}

// ---------------------------------------------------------------------------
// K1: q/k/v = W @ x + b.  grid (32 ntile, 3 which, B).
// Output: qT,kT [B][N][128] bf16 (pos-major), vC [B][128][N] bf16 (ch-major).
// ---------------------------------------------------------------------------
__global__ __launch_bounds__(256) void k_qkv(
    const float* __restrict__ Wq, const float* __restrict__ Wk, const float* __restrict__ Wv,
    const float* __restrict__ bq, const float* __restrict__ bk, const float* __restrict__ bv,
    const bf16* __restrict__ xT, bf16* __restrict__ qT, bf16* __restrict__ kT,
    bf16* __restrict__ vC) {
    __shared__ __align__(16) char a_lds[128 * 128];  // [128 m][64 k] bf16 swz
    __shared__ __align__(16) char b_lds[128 * 128];  // [128 n][64 k] bf16 swz
    int n0 = blockIdx.x * 128, which = blockIdx.y, b = blockIdx.z;
    const float* W    = which == 0 ? Wq : (which == 1 ? Wk : Wv);
    const float* bias = which == 0 ? bq : (which == 1 ? bk : bv);
    int t = threadIdx.x, lane = t & 63, w = t >> 6, wy = w >> 1, wx = w & 1;
    const bf16* xb = xT + (size_t)b * NPOS * CIN;

    f32x4 acc[4][4] = {};
    for (int k0 = 0; k0 < 256; k0 += 64) {
        __syncthreads();
        for (int i = 0; i < 8; ++i) {                 // A: W f32 -> bf16
            int idx = t + i * 256;                    // 2048 float4
            int row = idx >> 4, c4 = (idx & 15) * 4;
            f32x4 v = *reinterpret_cast<const f32x4*>(W + (size_t)row * CIN + k0 + c4);
            bf16x4 o; o[0] = (bf16)v[0]; o[1] = (bf16)v[1]; o[2] = (bf16)v[2]; o[3] = (bf16)v[3];
            *reinterpret_cast<bf16x4*>(a_lds + swz128(row, c4 * 2)) = o;
        }
        for (int i = 0; i < 4; ++i) {                 // B: xT bf16 copy
            int idx = t + i * 256;                    // 1024 16B chunks
            int row = idx >> 3, cb = (idx & 7) * 16;
            bf16x8 vv = *reinterpret_cast<const bf16x8*>(xb + (size_t)(n0 + row) * CIN + k0 + cb / 2);
            *reinterpret_cast<bf16x8*>(b_lds + swz128(row, cb)) = vv;
        }
        __syncthreads();
        for (int ks = 0; ks < 2; ++ks) {
            int kb = ks * 64 + (lane >> 4) * 16;
            bf16x8 af[4], bfr[4];
            for (int i = 0; i < 4; ++i)
                af[i] = *reinterpret_cast<const bf16x8*>(a_lds + swz128(wy * 64 + i * 16 + (lane & 15), kb));
            for (int j = 0; j < 4; ++j)
                bfr[j] = *reinterpret_cast<const bf16x8*>(b_lds + swz128(wx * 64 + j * 16 + (lane & 15), kb));
            for (int i = 0; i < 4; ++i)
                for (int j = 0; j < 4; ++j)
                    acc[i][j] = MFMA16(af[i], bfr[j], acc[i][j]);
        }
    }
    int rg = lane >> 4, cl = lane & 15;
    for (int i = 0; i < 4; ++i) {
        int ch0 = wy * 64 + i * 16 + rg * 4;
        f32x4 bv4 = *reinterpret_cast<const f32x4*>(bias + ch0);
        for (int j = 0; j < 4; ++j) {
            int n = n0 + wx * 64 + j * 16 + cl;
            f32x4 d = acc[i][j];
            for (int r = 0; r < 4; ++r) d[r] += bv4[r];
            if (which == 2) {
                for (int r = 0; r < 4; ++r)
                    vC[((size_t)b * CMID + ch0 + r) * NPOS + n] = (bf16)d[r];
            } else {
                bf16x4 o; o[0] = (bf16)d[0]; o[1] = (bf16)d[1]; o[2] = (bf16)d[2]; o[3] = (bf16)d[3];
                bf16* dst = (which == 0 ? qT : kT);
                *reinterpret_cast<bf16x4*>(dst + ((size_t)b * NPOS + n) * CMID + ch0) = o;
            }
        }
    }
}

// ---------------------------------------------------------------------------
// K2: invZ[n] = 1 / sum_m exp(S[n,m]),  S[n,m] = k[:,n].q[:,m].
// grid (64 ntile, B). Block owns 64 n, loops all m. S bounded (~±25): no max.
// ---------------------------------------------------------------------------
__global__ __launch_bounds__(256) void k_zrow(const bf16* __restrict__ qT,
                                              const bf16* __restrict__ kT,
                                              float* __restrict__ invZ) {
    __shared__ __align__(16) char k_lds[64 * 256];  // [64 n][128 c] bf16 swz
    __shared__ __align__(16) char q_lds[64 * 256];  // [64 m][128 c] bf16 swz
    int n0 = blockIdx.x * 64, b = blockIdx.y;
    int t = threadIdx.x, lane = t & 63, w = t >> 6;
    const bf16* qb = qT + (size_t)b * NPOS * CMID;
    const bf16* kb = kT + (size_t)b * NPOS * CMID;
    for (int i = 0; i < 4; ++i) {                    // stage k-tile once
        int idx = t + i * 256, row = idx >> 4, cb = (idx & 15) * 16;
        bf16x8 vv = *reinterpret_cast<const bf16x8*>(kb + (size_t)(n0 + row) * CMID + cb / 2);
        *reinterpret_cast<bf16x8*>(k_lds + swz256(row, cb)) = vv;
    }
    float zacc = 0.f;
    for (int m0 = 0; m0 < NPOS; m0 += 64) {
        __syncthreads();
        for (int i = 0; i < 4; ++i) {
            int idx = t + i * 256, row = idx >> 4, cb = (idx & 15) * 16;
            bf16x8 vv = *reinterpret_cast<const bf16x8*>(qb + (size_t)(m0 + row) * CMID + cb / 2);
            *reinterpret_cast<bf16x8*>(q_lds + swz256(row, cb)) = vv;
        }
        __syncthreads();
        f32x4 acc[4] = {};
        for (int ks = 0; ks < 4; ++ks) {
            int kb_ = ks * 64 + (lane >> 4) * 16;
            bf16x8 bfr = *reinterpret_cast<const bf16x8*>(k_lds + swz256(w * 16 + (lane & 15), kb_));
            for (int i = 0; i < 4; ++i) {
                bf16x8 af = *reinterpret_cast<const bf16x8*>(q_lds + swz256(i * 16 + (lane & 15), kb_));
                acc[i] = MFMA16(af, bfr, acc[i]);
            }
        }
        for (int i = 0; i < 4; ++i)
            for (int r = 0; r < 4; ++r)
                zacc += __expf(acc[i][r]);
    }
    zacc += __shfl_xor(zacc, 16);
    zacc += __shfl_xor(zacc, 32);
    if ((lane >> 4) == 0)
        invZ[(size_t)b * NPOS + n0 + w * 16 + lane] = 1.f / zacc;
}

// ---------------------------------------------------------------------------
// K4: yT[m][c] = sum_n P[n,m] v[c,n],  P = exp(S)*invZ[n]  (P in (0,1]).
// grid (64 mtile, B). Fused S-GEMM -> exp -> LDS P -> PV-GEMM.
// ---------------------------------------------------------------------------
__global__ __launch_bounds__(256) void k_attn(const bf16* __restrict__ qT,
                                              const bf16* __restrict__ kT,
                                              const bf16* __restrict__ vC,
                                              const float* __restrict__ invZ,
                                              float* __restrict__ yT) {
    __shared__ __align__(16) char q_lds[64 * 256];   // [64 m][128 c]
    __shared__ __align__(16) char k_lds[64 * 256];   // [64 n][128 c]
    __shared__ __align__(16) char v_lds[128 * 128];  // [128 c][64 n]
    __shared__ __align__(16) char p_lds[64 * 128];   // [64 m][64 n]
    int m0 = blockIdx.x * 64, b = blockIdx.y;
    int t = threadIdx.x, lane = t & 63, w = t >> 6;
    const bf16* qb = qT + (size_t)b * NPOS * CMID;
    const bf16* kb = kT + (size_t)b * NPOS * CMID;
    const bf16* vb = vC + (size_t)b * CMID * NPOS;
    const float* izb = invZ + (size_t)b * NPOS;
    for (int i = 0; i < 4; ++i) {                    // stage q-tile once
        int idx = t + i * 256, row = idx >> 4, cb = (idx & 15) * 16;
        bf16x8 vv = *reinterpret_cast<const bf16x8*>(qb + (size_t)(m0 + row) * CMID + cb / 2);
        *reinterpret_cast<bf16x8*>(q_lds + swz256(row, cb)) = vv;
    }
    f32x4 acc2[4][2] = {};
    for (int n0 = 0; n0 < NPOS; n0 += 64) {
        __syncthreads();
        for (int i = 0; i < 4; ++i) {                // stage k-tile
            int idx = t + i * 256, row = idx >> 4, cb = (idx & 15) * 16;
            bf16x8 vv = *reinterpret_cast<const bf16x8*>(kb + (size_t)(n0 + row) * CMID + cb / 2);
            *reinterpret_cast<bf16x8*>(k_lds + swz256(row, cb)) = vv;
        }
        for (int i = 0; i < 4; ++i) {                // stage v-tile
            int idx = t + i * 256, row = idx >> 3, cb = (idx & 7) * 16;
            bf16x8 vv = *reinterpret_cast<const bf16x8*>(vb + (size_t)row * NPOS + n0 + cb / 2);
            *reinterpret_cast<bf16x8*>(v_lds + swz128(row, cb)) = vv;
        }
        __syncthreads();
        f32x4 acc1[4] = {};                          // S^T[m 64][n: w*16+cl]
        for (int ks = 0; ks < 4; ++ks) {
            int kb_ = ks * 64 + (lane >> 4) * 16;
            bf16x8 bfr = *reinterpret_cast<const bf16x8*>(k_lds + swz256(w * 16 + (lane & 15), kb_));
            for (int i = 0; i < 4; ++i) {
                bf16x8 af = *reinterpret_cast<const bf16x8*>(q_lds + swz256(i * 16 + (lane & 15), kb_));
                acc1[i] = MFMA16(af, bfr, acc1[i]);
            }
        }
        int nl = w * 16 + (lane & 15);
        float iz = izb[n0 + nl];
        int rg = lane >> 4;
        for (int i = 0; i < 4; ++i)
            for (int r = 0; r < 4; ++r) {
                float p = __expf(acc1[i][r]) * iz;
                int m = i * 16 + rg * 4 + r;
                *reinterpret_cast<bf16*>(p_lds + swz128(m, nl * 2)) = (bf16)p;
            }
        __syncthreads();
        for (int ks = 0; ks < 2; ++ks) {             // PV: wave owns c-chunk w*32
            int kb_ = ks * 64 + (lane >> 4) * 16;
            bf16x8 af[4], bfr[2];
            for (int i = 0; i < 4; ++i)
                af[i] = *reinterpret_cast<const bf16x8*>(p_lds + swz128(i * 16 + (lane & 15), kb_));
            for (int j = 0; j < 2; ++j)
                bfr[j] = *reinterpret_cast<const bf16x8*>(v_lds + swz128(w * 32 + j * 16 + (lane & 15), kb_));
            for (int i = 0; i < 4; ++i)
                for (int j = 0; j < 2; ++j)
                    acc2[i][j] = MFMA16(af[i], bfr[j], acc2[i][j]);
        }
    }
    int rg = lane >> 4, cl = lane & 15;
    float* yb = yT + ((size_t)b * NPOS + m0) * CMID;
    for (int i = 0; i < 4; ++i)
        for (int j = 0; j < 2; ++j) {
            int c = w * 32 + j * 16 + cl;
            for (int r = 0; r < 4; ++r) {
                int m = i * 16 + rg * 4 + r;
                yb[(size_t)m * CMID + c] = acc2[i][j][r];
            }
        }
}

// ---------------------------------------------------------------------------
// K5: out = (Ww @ y + bw)*inv + add + x.  grid (32 mtile, 2 otile, B).
// ---------------------------------------------------------------------------
__global__ __launch_bounds__(256) void k_out(
    const float* __restrict__ Ww, const float* __restrict__ bw,
    const float* __restrict__ gamma, const float* __restrict__ beta,
    const float* __restrict__ mean, const float* __restrict__ var,
    const float* __restrict__ yT, const float* __restrict__ x,
    float* __restrict__ out) {
    __shared__ __align__(16) char a_lds[128 * 128];  // [128 o][64 c] bf16 swz
    __shared__ __align__(16) char b_lds[128 * 128];  // [128 m][64 c] bf16 swz
    int m0 = blockIdx.x * 128, o0 = blockIdx.y * 128, b = blockIdx.z;
    int t = threadIdx.x, lane = t & 63, w = t >> 6, wy = w >> 1, wx = w & 1;
    f32x4 acc[4][4] = {};
    for (int k0 = 0; k0 < 128; k0 += 64) {
        __syncthreads();
        for (int i = 0; i < 8; ++i) {
            int idx = t + i * 256, row = idx >> 4, c4 = (idx & 15) * 4;
            f32x4 v = *reinterpret_cast<const f32x4*>(Ww + (size_t)(o0 + row) * CMID + k0 + c4);
            bf16x4 o; o[0] = (bf16)v[0]; o[1] = (bf16)v[1]; o[2] = (bf16)v[2]; o[3] = (bf16)v[3];
            *reinterpret_cast<bf16x4*>(a_lds + swz128(row, c4 * 2)) = o;
        }
        for (int i = 0; i < 8; ++i) {
            int idx = t + i * 256, row = idx >> 4, c4 = (idx & 15) * 4;
            f32x4 v = *reinterpret_cast<const f32x4*>(yT + ((size_t)b * NPOS + m0 + row) * CMID + k0 + c4);
            bf16x4 o; o[0] = (bf16)v[0]; o[1] = (bf16)v[1]; o[2] = (bf16)v[2]; o[3] = (bf16)v[3];
            *reinterpret_cast<bf16x4*>(b_lds + swz128(row, c4 * 2)) = o;
        }
        __syncthreads();
        for (int ks = 0; ks < 2; ++ks) {
            int kb = ks * 64 + (lane >> 4) * 16;
            bf16x8 af[4], bfr[4];
            for (int i = 0; i < 4; ++i)
                af[i] = *reinterpret_cast<const bf16x8*>(a_lds + swz128(wy * 64 + i * 16 + (lane & 15), kb));
            for (int j = 0; j < 4; ++j)
                bfr[j] = *reinterpret_cast<const bf16x8*>(b_lds + swz128(wx * 64 + j * 16 + (lane & 15), kb));
            for (int i = 0; i < 4; ++i)
                for (int j = 0; j < 4; ++j)
                    acc[i][j] = MFMA16(af[i], bfr[j], acc[i][j]);
        }
    }
    int rg = lane >> 4, cl = lane & 15;
    const float* xb = x + (size_t)b * CIN * NPOS;
    float* ob = out + (size_t)b * CIN * NPOS;
    for (int i = 0; i < 4; ++i) {
        int och0 = o0 + wy * 64 + i * 16 + rg * 4;
        f32x4 g  = *reinterpret_cast<const f32x4*>(gamma + och0);
        f32x4 be = *reinterpret_cast<const f32x4*>(beta + och0);
        f32x4 mu = *reinterpret_cast<const f32x4*>(mean + och0);
        f32x4 va = *reinterpret_cast<const f32x4*>(var + och0);
        f32x4 bb = *reinterpret_cast<const f32x4*>(bw + och0);
        float invv[4], addv[4];
        for (int r = 0; r < 4; ++r) {
            invv[r] = g[r] / sqrtf(va[r] + EPS);
            addv[r] = be[r] - mu[r] * invv[r];
        }
        for (int j = 0; j < 4; ++j) {
            int m = m0 + wx * 64 + j * 16 + cl;
            for (int r = 0; r < 4; ++r) {
                float z = (acc[i][j][r] + bb[r]) * invv[r] + addv[r];
                ob[(size_t)(och0 + r) * NPOS + m] = z + xb[(size_t)(och0 + r) * NPOS + m];
            }
        }
    }
}

// ---------------------------------------------------------------------------
extern "C" void kernel_launch(void* const* d_in, const int* in_sizes, int n_in,
                              void* d_out, int out_size, void* d_ws, size_t ws_size,
                              hipStream_t stream) {
    const float* x     = (const float*)d_in[0];
    const float* Wq    = (const float*)d_in[1];
    const float* bq    = (const float*)d_in[2];
    const float* Wk    = (const float*)d_in[3];
    const float* bk    = (const float*)d_in[4];
    const float* Wv    = (const float*)d_in[5];
    const float* bv    = (const float*)d_in[6];
    const float* Ww    = (const float*)d_in[7];
    const float* bw    = (const float*)d_in[8];
    const float* gamma = (const float*)d_in[9];
    const float* beta  = (const float*)d_in[10];
    const float* mean  = (const float*)d_in[11];
    const float* var   = (const float*)d_in[12];
    float* out = (float*)d_out;

    char* ws = (char*)d_ws;
    bf16* xT = (bf16*)ws;      ws += (size_t)BATCH * NPOS * CIN * 2;   // 8 MB
    bf16* qT = (bf16*)ws;      ws += (size_t)BATCH * NPOS * CMID * 2;  // 4 MB
    bf16* kT = (bf16*)ws;      ws += (size_t)BATCH * NPOS * CMID * 2;  // 4 MB
    bf16* vC = (bf16*)ws;      ws += (size_t)BATCH * NPOS * CMID * 2;  // 4 MB
    float* invZ = (float*)ws;  ws += (size_t)BATCH * NPOS * 4;         // 64 KB
    float* yT = (float*)ws;                                            // 8 MB

    kt_transpose<<<dim3(NPOS / 64, CIN / 64, BATCH), 256, 0, stream>>>(x, xT);
    k_qkv<<<dim3(NPOS / 128, 3, BATCH), 256, 0, stream>>>(Wq, Wk, Wv, bq, bk, bv, xT, qT, kT, vC);
    k_zrow<<<dim3(NPOS / 64, BATCH), 256, 0, stream>>>(qT, kT, invZ);
    k_attn<<<dim3(NPOS / 64, BATCH), 256, 0, stream>>>(qT, kT, vC, invZ, yT);
    k_out<<<dim3(NPOS / 128, 2, BATCH), 256, 0, stream>>>(Ww, bw, gamma, beta, mean, var, yT, x, out);
}

// Round 3
// 136.717 us; speedup vs baseline: 1.4355x; 1.4355x over previous
//
#include <hip/hip_runtime.h>
#include <hip/hip_bf16.h>

#define BATCH 4
#define CIN   256
#define CMID  128
#define NPOS  4096
#define EPS   1e-5f

typedef __bf16 bf16;
typedef __attribute__((ext_vector_type(8))) __bf16 bf16x8;
typedef __attribute__((ext_vector_type(4))) __bf16 bf16x4;
typedef __attribute__((ext_vector_type(4))) float  f32x4;

#define MFMA16(a, b, c) __builtin_amdgcn_mfma_f32_16x16x32_bf16((a), (b), (c), 0, 0, 0)

// XOR swizzle: 16B chunks within a row, chunk ^= (row & 7). Bijective, kills
// the 16-way bank conflict of row-major bf16 tiles read 16-rows-at-a-time.
__device__ __forceinline__ int swz128(int row, int colb) {
    return row * 128 + ((((colb >> 4) ^ (row & 7)) << 4) | (colb & 15));
}
__device__ __forceinline__ int swz256(int row, int colb) {
    return row * 256 + ((((colb >> 4) ^ (row & 7)) << 4) | (colb & 15));
}

// ---------------------------------------------------------------------------
// KT: x [B][CIN][N] f32  ->  xT [B][N][CIN] bf16   (LDS 64x64 tile transpose)
// ---------------------------------------------------------------------------
__global__ __launch_bounds__(256) void kt_transpose(const float* __restrict__ x,
                                                    bf16* __restrict__ xT) {
    __shared__ float tile[64][65];
    int n0 = blockIdx.x * 64, c0 = blockIdx.y * 64, b = blockIdx.z;
    const float* xp = x + (size_t)b * CIN * NPOS;
    int t = threadIdx.x;
    int lr = t >> 4;            // 0..15
    int lc4 = (t & 15) * 4;     // 0..60
    for (int p = 0; p < 4; ++p) {
        int c = lr + p * 16;
        f32x4 v = *reinterpret_cast<const f32x4*>(xp + (size_t)(c0 + c) * NPOS + n0 + lc4);
        tile[c][lc4 + 0] = v[0]; tile[c][lc4 + 1] = v[1];
        tile[c][lc4 + 2] = v[2]; tile[c][lc4 + 3] = v[3];
    }
    __syncthreads();
    bf16* xtp = xT + (size_t)b * NPOS * CIN;
    int cc = (t & 15) * 4;
    for (int p = 0; p < 4; ++p) {
        int n = (t >> 4) + p * 16;
        bf16x4 o;
        o[0] = (bf16)tile[cc + 0][n]; o[1] = (bf16)tile[cc + 1][n];
        o[2] = (bf16)tile[cc + 2][n]; o[3] = (bf16)tile[cc + 3][n];
        *reinterpret_cast<bf16x4*>(xtp + (size_t)(n0 + n) * CIN + c0 + cc) = o;
    }
}

// ---------------------------------------------------------------------------
// K1: q/k/v = W @ x + b.  grid (32 ntile, 3 which, B).
// Output: qT,kT [B][N][128] bf16 (pos-major), vC [B][128][N] bf16 (ch-major).
// ---------------------------------------------------------------------------
__global__ __launch_bounds__(256) void k_qkv(
    const float* __restrict__ Wq, const float* __restrict__ Wk, const float* __restrict__ Wv,
    const float* __restrict__ bq, const float* __restrict__ bk, const float* __restrict__ bv,
    const bf16* __restrict__ xT, bf16* __restrict__ qT, bf16* __restrict__ kT,
    bf16* __restrict__ vC) {
    __shared__ __align__(16) char a_lds[128 * 128];  // [128 m][64 k] bf16 swz
    __shared__ __align__(16) char b_lds[128 * 128];  // [128 n][64 k] bf16 swz
    int n0 = blockIdx.x * 128, which = blockIdx.y, b = blockIdx.z;
    const float* W    = which == 0 ? Wq : (which == 1 ? Wk : Wv);
    const float* bias = which == 0 ? bq : (which == 1 ? bk : bv);
    int t = threadIdx.x, lane = t & 63, w = t >> 6, wy = w >> 1, wx = w & 1;
    const bf16* xb = xT + (size_t)b * NPOS * CIN;

    f32x4 acc[4][4] = {};
    for (int k0 = 0; k0 < 256; k0 += 64) {
        __syncthreads();
        for (int i = 0; i < 8; ++i) {                 // A: W f32 -> bf16
            int idx = t + i * 256;                    // 2048 float4
            int row = idx >> 4, c4 = (idx & 15) * 4;
            f32x4 v = *reinterpret_cast<const f32x4*>(W + (size_t)row * CIN + k0 + c4);
            bf16x4 o; o[0] = (bf16)v[0]; o[1] = (bf16)v[1]; o[2] = (bf16)v[2]; o[3] = (bf16)v[3];
            *reinterpret_cast<bf16x4*>(a_lds + swz128(row, c4 * 2)) = o;
        }
        for (int i = 0; i < 4; ++i) {                 // B: xT bf16 copy
            int idx = t + i * 256;                    // 1024 16B chunks
            int row = idx >> 3, cb = (idx & 7) * 16;
            bf16x8 vv = *reinterpret_cast<const bf16x8*>(xb + (size_t)(n0 + row) * CIN + k0 + cb / 2);
            *reinterpret_cast<bf16x8*>(b_lds + swz128(row, cb)) = vv;
        }
        __syncthreads();
        for (int ks = 0; ks < 2; ++ks) {
            int kb = ks * 64 + (lane >> 4) * 16;
            bf16x8 af[4], bfr[4];
            for (int i = 0; i < 4; ++i)
                af[i] = *reinterpret_cast<const bf16x8*>(a_lds + swz128(wy * 64 + i * 16 + (lane & 15), kb));
            for (int j = 0; j < 4; ++j)
                bfr[j] = *reinterpret_cast<const bf16x8*>(b_lds + swz128(wx * 64 + j * 16 + (lane & 15), kb));
            for (int i = 0; i < 4; ++i)
                for (int j = 0; j < 4; ++j)
                    acc[i][j] = MFMA16(af[i], bfr[j], acc[i][j]);
        }
    }
    int rg = lane >> 4, cl = lane & 15;
    for (int i = 0; i < 4; ++i) {
        int ch0 = wy * 64 + i * 16 + rg * 4;
        f32x4 bv4 = *reinterpret_cast<const f32x4*>(bias + ch0);
        for (int j = 0; j < 4; ++j) {
            int n = n0 + wx * 64 + j * 16 + cl;
            f32x4 d = acc[i][j];
            for (int r = 0; r < 4; ++r) d[r] += bv4[r];
            if (which == 2) {
                for (int r = 0; r < 4; ++r)
                    vC[((size_t)b * CMID + ch0 + r) * NPOS + n] = (bf16)d[r];
            } else {
                bf16x4 o; o[0] = (bf16)d[0]; o[1] = (bf16)d[1]; o[2] = (bf16)d[2]; o[3] = (bf16)d[3];
                bf16* dst = (which == 0 ? qT : kT);
                *reinterpret_cast<bf16x4*>(dst + ((size_t)b * NPOS + n) * CMID + ch0) = o;
            }
        }
    }
}

// ---------------------------------------------------------------------------
// K2: zpart[mh][b][n] = sum_{m in half mh} exp(S[n,m]),  S[n,m] = k[:,n].q[:,m].
// grid (64 ntile, 2 mhalf, B). Block owns 64 n, loops its m-half.
// S bounded (~±25): no max subtraction needed.
// ---------------------------------------------------------------------------
__global__ __launch_bounds__(256) void k_zrow(const bf16* __restrict__ qT,
                                              const bf16* __restrict__ kT,
                                              float* __restrict__ zpart) {
    __shared__ __align__(16) char k_lds[64 * 256];  // [64 n][128 c] bf16 swz
    __shared__ __align__(16) char q_lds[64 * 256];  // [64 m][128 c] bf16 swz
    int n0 = blockIdx.x * 64, mh = blockIdx.y, b = blockIdx.z;
    int t = threadIdx.x, lane = t & 63, w = t >> 6;
    const bf16* qb = qT + (size_t)b * NPOS * CMID;
    const bf16* kb = kT + (size_t)b * NPOS * CMID;
    for (int i = 0; i < 4; ++i) {                    // stage k-tile once
        int idx = t + i * 256, row = idx >> 4, cb = (idx & 15) * 16;
        bf16x8 vv = *reinterpret_cast<const bf16x8*>(kb + (size_t)(n0 + row) * CMID + cb / 2);
        *reinterpret_cast<bf16x8*>(k_lds + swz256(row, cb)) = vv;
    }
    float zacc = 0.f;
    int mbeg = mh * (NPOS / 2), mend = mbeg + NPOS / 2;
    for (int m0 = mbeg; m0 < mend; m0 += 64) {
        __syncthreads();
        for (int i = 0; i < 4; ++i) {
            int idx = t + i * 256, row = idx >> 4, cb = (idx & 15) * 16;
            bf16x8 vv = *reinterpret_cast<const bf16x8*>(qb + (size_t)(m0 + row) * CMID + cb / 2);
            *reinterpret_cast<bf16x8*>(q_lds + swz256(row, cb)) = vv;
        }
        __syncthreads();
        f32x4 acc[4] = {};
        for (int ks = 0; ks < 4; ++ks) {
            int kb_ = ks * 64 + (lane >> 4) * 16;
            bf16x8 bfr = *reinterpret_cast<const bf16x8*>(k_lds + swz256(w * 16 + (lane & 15), kb_));
            for (int i = 0; i < 4; ++i) {
                bf16x8 af = *reinterpret_cast<const bf16x8*>(q_lds + swz256(i * 16 + (lane & 15), kb_));
                acc[i] = MFMA16(af, bfr, acc[i]);
            }
        }
        for (int i = 0; i < 4; ++i)
            for (int r = 0; r < 4; ++r)
                zacc += __expf(acc[i][r]);
    }
    zacc += __shfl_xor(zacc, 16);
    zacc += __shfl_xor(zacc, 32);
    if ((lane >> 4) == 0)
        zpart[((size_t)mh * BATCH + b) * NPOS + n0 + w * 16 + lane] = zacc;
}

// ---------------------------------------------------------------------------
// K3: invZ = 1 / (zpart[0] + zpart[1]).   16384 elems, f32x4.
// ---------------------------------------------------------------------------
__global__ __launch_bounds__(256) void k_rcp(const float* __restrict__ zpart,
                                             float* __restrict__ invZ) {
    int i = (blockIdx.x * 256 + threadIdx.x) * 4;
    f32x4 a = *reinterpret_cast<const f32x4*>(zpart + i);
    f32x4 c = *reinterpret_cast<const f32x4*>(zpart + BATCH * NPOS + i);
    f32x4 o;
    for (int r = 0; r < 4; ++r) o[r] = 1.f / (a[r] + c[r]);
    *reinterpret_cast<f32x4*>(invZ + i) = o;
}

// ---------------------------------------------------------------------------
// K4: yT[m][c] = sum_n P[n,m] v[c,n],  P = exp(S)*invZ[n]  (P in (0,1]).
// grid (64 mtile, 2 nhalf, B): each block does half the n-reduction into its
// own partial buffer yT0/yT1 (summed in k_out). 512 blocks -> 2 blocks/CU.
// S-MFMA is mfma(k,q) so each lane holds 4 consecutive n -> 8B P-writes.
// ---------------------------------------------------------------------------
__global__ __launch_bounds__(256) void k_attn(const bf16* __restrict__ qT,
                                              const bf16* __restrict__ kT,
                                              const bf16* __restrict__ vC,
                                              const float* __restrict__ invZ,
                                              float* __restrict__ yT0,
                                              float* __restrict__ yT1) {
    __shared__ __align__(16) char q_lds[64 * 256];   // [64 m][128 c]
    __shared__ __align__(16) char k_lds[64 * 256];   // [64 n][128 c]
    __shared__ __align__(16) char v_lds[128 * 128];  // [128 c][64 n]
    __shared__ __align__(16) char p_lds[64 * 128];   // [64 m][64 n] = P^T
    int m0 = blockIdx.x * 64, nh = blockIdx.y, b = blockIdx.z;
    int t = threadIdx.x, lane = t & 63, w = t >> 6;
    int cl = lane & 15, rg = lane >> 4;
    const bf16* qb = qT + (size_t)b * NPOS * CMID;
    const bf16* kb = kT + (size_t)b * NPOS * CMID;
    const bf16* vb = vC + (size_t)b * CMID * NPOS;
    const float* izb = invZ + (size_t)b * NPOS;
    for (int i = 0; i < 4; ++i) {                    // stage q-tile once
        int idx = t + i * 256, row = idx >> 4, cb = (idx & 15) * 16;
        bf16x8 vv = *reinterpret_cast<const bf16x8*>(qb + (size_t)(m0 + row) * CMID + cb / 2);
        *reinterpret_cast<bf16x8*>(q_lds + swz256(row, cb)) = vv;
    }
    f32x4 acc2[4][2] = {};
    int nbeg = nh * (NPOS / 2), nend = nbeg + NPOS / 2;
    for (int n0 = nbeg; n0 < nend; n0 += 64) {
        __syncthreads();
        for (int i = 0; i < 4; ++i) {                // stage k-tile
            int idx = t + i * 256, row = idx >> 4, cb = (idx & 15) * 16;
            bf16x8 vv = *reinterpret_cast<const bf16x8*>(kb + (size_t)(n0 + row) * CMID + cb / 2);
            *reinterpret_cast<bf16x8*>(k_lds + swz256(row, cb)) = vv;
        }
        for (int i = 0; i < 4; ++i) {                // stage v-tile
            int idx = t + i * 256, row = idx >> 3, cb = (idx & 7) * 16;
            bf16x8 vv = *reinterpret_cast<const bf16x8*>(vb + (size_t)row * NPOS + n0 + cb / 2);
            *reinterpret_cast<bf16x8*>(v_lds + swz128(row, cb)) = vv;
        }
        __syncthreads();
        // S^T: acc1[i] = D[n = i*16+rg*4+r][m = w*16+cl]
        f32x4 acc1[4] = {};
        for (int ks = 0; ks < 4; ++ks) {
            int kb_ = ks * 64 + rg * 16;
            bf16x8 qf = *reinterpret_cast<const bf16x8*>(q_lds + swz256(w * 16 + cl, kb_));
            for (int i = 0; i < 4; ++i) {
                bf16x8 kf = *reinterpret_cast<const bf16x8*>(k_lds + swz256(i * 16 + cl, kb_));
                acc1[i] = MFMA16(kf, qf, acc1[i]);
            }
        }
        // P^T[m][n] = exp(S)*invZ[n]; lane writes 4 consecutive n (8B).
        int mrow = w * 16 + cl;
        for (int i = 0; i < 4; ++i) {
            f32x4 zq = *reinterpret_cast<const f32x4*>(izb + n0 + i * 16 + rg * 4);
            bf16x4 o;
            for (int r = 0; r < 4; ++r) o[r] = (bf16)(__expf(acc1[i][r]) * zq[r]);
            *reinterpret_cast<bf16x4*>(p_lds + swz128(mrow, i * 32 + rg * 8)) = o;
        }
        __syncthreads();
        for (int ks = 0; ks < 2; ++ks) {             // PV: wave owns c-chunk w*32
            int kb_ = ks * 64 + rg * 16;
            bf16x8 af[4], bfr[2];
            for (int i = 0; i < 4; ++i)
                af[i] = *reinterpret_cast<const bf16x8*>(p_lds + swz128(i * 16 + cl, kb_));
            for (int j = 0; j < 2; ++j)
                bfr[j] = *reinterpret_cast<const bf16x8*>(v_lds + swz128(w * 32 + j * 16 + cl, kb_));
            for (int i = 0; i < 4; ++i)
                for (int j = 0; j < 2; ++j)
                    acc2[i][j] = MFMA16(af[i], bfr[j], acc2[i][j]);
        }
    }
    float* yb = (nh ? yT1 : yT0) + ((size_t)b * NPOS + m0) * CMID;
    for (int i = 0; i < 4; ++i)
        for (int j = 0; j < 2; ++j) {
            int c = w * 32 + j * 16 + cl;
            for (int r = 0; r < 4; ++r) {
                int m = i * 16 + rg * 4 + r;
                yb[(size_t)m * CMID + c] = acc2[i][j][r];
            }
        }
}

// ---------------------------------------------------------------------------
// K5: out = (Ww @ (y0+y1) + bw)*inv + add + x.  grid (32 mtile, 2 otile, B).
// ---------------------------------------------------------------------------
__global__ __launch_bounds__(256) void k_out(
    const float* __restrict__ Ww, const float* __restrict__ bw,
    const float* __restrict__ gamma, const float* __restrict__ beta,
    const float* __restrict__ mean, const float* __restrict__ var,
    const float* __restrict__ yT0, const float* __restrict__ yT1,
    const float* __restrict__ x, float* __restrict__ out) {
    __shared__ __align__(16) char a_lds[128 * 128];  // [128 o][64 c] bf16 swz
    __shared__ __align__(16) char b_lds[128 * 128];  // [128 m][64 c] bf16 swz
    int m0 = blockIdx.x * 128, o0 = blockIdx.y * 128, b = blockIdx.z;
    int t = threadIdx.x, lane = t & 63, w = t >> 6, wy = w >> 1, wx = w & 1;
    f32x4 acc[4][4] = {};
    for (int k0 = 0; k0 < 128; k0 += 64) {
        __syncthreads();
        for (int i = 0; i < 8; ++i) {
            int idx = t + i * 256, row = idx >> 4, c4 = (idx & 15) * 4;
            f32x4 v = *reinterpret_cast<const f32x4*>(Ww + (size_t)(o0 + row) * CMID + k0 + c4);
            bf16x4 o; o[0] = (bf16)v[0]; o[1] = (bf16)v[1]; o[2] = (bf16)v[2]; o[3] = (bf16)v[3];
            *reinterpret_cast<bf16x4*>(a_lds + swz128(row, c4 * 2)) = o;
        }
        for (int i = 0; i < 8; ++i) {
            int idx = t + i * 256, row = idx >> 4, c4 = (idx & 15) * 4;
            size_t yoff = ((size_t)b * NPOS + m0 + row) * CMID + k0 + c4;
            f32x4 v0 = *reinterpret_cast<const f32x4*>(yT0 + yoff);
            f32x4 v1 = *reinterpret_cast<const f32x4*>(yT1 + yoff);
            bf16x4 o;
            for (int r = 0; r < 4; ++r) o[r] = (bf16)(v0[r] + v1[r]);
            *reinterpret_cast<bf16x4*>(b_lds + swz128(row, c4 * 2)) = o;
        }
        __syncthreads();
        for (int ks = 0; ks < 2; ++ks) {
            int kb = ks * 64 + (lane >> 4) * 16;
            bf16x8 af[4], bfr[4];
            for (int i = 0; i < 4; ++i)
                af[i] = *reinterpret_cast<const bf16x8*>(a_lds + swz128(wy * 64 + i * 16 + (lane & 15), kb));
            for (int j = 0; j < 4; ++j)
                bfr[j] = *reinterpret_cast<const bf16x8*>(b_lds + swz128(wx * 64 + j * 16 + (lane & 15), kb));
            for (int i = 0; i < 4; ++i)
                for (int j = 0; j < 4; ++j)
                    acc[i][j] = MFMA16(af[i], bfr[j], acc[i][j]);
        }
    }
    int rg = lane >> 4, cl = lane & 15;
    const float* xb = x + (size_t)b * CIN * NPOS;
    float* ob = out + (size_t)b * CIN * NPOS;
    for (int i = 0; i < 4; ++i) {
        int och0 = o0 + wy * 64 + i * 16 + rg * 4;
        f32x4 g  = *reinterpret_cast<const f32x4*>(gamma + och0);
        f32x4 be = *reinterpret_cast<const f32x4*>(beta + och0);
        f32x4 mu = *reinterpret_cast<const f32x4*>(mean + och0);
        f32x4 va = *reinterpret_cast<const f32x4*>(var + och0);
        f32x4 bb = *reinterpret_cast<const f32x4*>(bw + och0);
        float invv[4], addv[4];
        for (int r = 0; r < 4; ++r) {
            invv[r] = g[r] / sqrtf(va[r] + EPS);
            addv[r] = be[r] - mu[r] * invv[r];
        }
        for (int j = 0; j < 4; ++j) {
            int m = m0 + wx * 64 + j * 16 + cl;
            for (int r = 0; r < 4; ++r) {
                float z = (acc[i][j][r] + bb[r]) * invv[r] + addv[r];
                ob[(size_t)(och0 + r) * NPOS + m] = z + xb[(size_t)(och0 + r) * NPOS + m];
            }
        }
    }
}

// ---------------------------------------------------------------------------
extern "C" void kernel_launch(void* const* d_in, const int* in_sizes, int n_in,
                              void* d_out, int out_size, void* d_ws, size_t ws_size,
                              hipStream_t stream) {
    const float* x     = (const float*)d_in[0];
    const float* Wq    = (const float*)d_in[1];
    const float* bq    = (const float*)d_in[2];
    const float* Wk    = (const float*)d_in[3];
    const float* bk    = (const float*)d_in[4];
    const float* Wv    = (const float*)d_in[5];
    const float* bv    = (const float*)d_in[6];
    const float* Ww    = (const float*)d_in[7];
    const float* bw    = (const float*)d_in[8];
    const float* gamma = (const float*)d_in[9];
    const float* beta  = (const float*)d_in[10];
    const float* mean  = (const float*)d_in[11];
    const float* var   = (const float*)d_in[12];
    float* out = (float*)d_out;

    char* ws = (char*)d_ws;
    // Region A (8MB): xT during kt/k_qkv, then reused as yT0 by k_attn.
    char* regionA = ws;                    ws += (size_t)BATCH * NPOS * CIN * 2;   // 8 MB
    bf16* qT = (bf16*)ws;                  ws += (size_t)BATCH * NPOS * CMID * 2;  // 4 MB
    bf16* kT = (bf16*)ws;                  ws += (size_t)BATCH * NPOS * CMID * 2;  // 4 MB
    bf16* vC = (bf16*)ws;                  ws += (size_t)BATCH * NPOS * CMID * 2;  // 4 MB
    float* yT1 = (float*)ws;               ws += (size_t)BATCH * NPOS * CMID * 4;  // 8 MB
    float* zpart = (float*)ws;             ws += (size_t)2 * BATCH * NPOS * 4;     // 128 KB
    float* invZ = (float*)ws;                                                     // 64 KB
    bf16*  xT  = (bf16*)regionA;
    float* yT0 = (float*)regionA;          // valid after k_qkv no longer needs xT

    kt_transpose<<<dim3(NPOS / 64, CIN / 64, BATCH), 256, 0, stream>>>(x, xT);
    k_qkv<<<dim3(NPOS / 128, 3, BATCH), 256, 0, stream>>>(Wq, Wk, Wv, bq, bk, bv, xT, qT, kT, vC);
    k_zrow<<<dim3(NPOS / 64, 2, BATCH), 256, 0, stream>>>(qT, kT, zpart);
    k_rcp<<<dim3(BATCH * NPOS / 1024), 256, 0, stream>>>(zpart, invZ);
    k_attn<<<dim3(NPOS / 64, 2, BATCH), 256, 0, stream>>>(qT, kT, vC, invZ, yT0, yT1);
    k_out<<<dim3(NPOS / 128, 2, BATCH), 256, 0, stream>>>(Ww, bw, gamma, beta, mean, var, yT0, yT1, x, out);
}

// Round 4
// 101.350 us; speedup vs baseline: 1.9365x; 1.3490x over previous
//
#include <hip/hip_runtime.h>
#include <hip/hip_bf16.h>

#define BATCH 4
#define CIN   256
#define CMID  128
#define NPOS  4096
#define EPS   1e-5f

typedef __bf16 bf16;
typedef __attribute__((ext_vector_type(8))) __bf16 bf16x8;
typedef __attribute__((ext_vector_type(4))) __bf16 bf16x4;
typedef __attribute__((ext_vector_type(4))) float  f32x4;

#define MFMA16(a, b, c) __builtin_amdgcn_mfma_f32_16x16x32_bf16((a), (b), (c), 0, 0, 0)

// XOR swizzle: 16B chunks within a row, chunk ^= (row & 7). Bijective, kills
// the bank conflicts of row-major bf16 tiles read 16-rows-at-a-time.
__device__ __forceinline__ int swz128(int row, int colb) {
    return row * 128 + ((((colb >> 4) ^ (row & 7)) << 4) | (colb & 15));
}
__device__ __forceinline__ int swz256(int row, int colb) {
    return row * 256 + ((((colb >> 4) ^ (row & 7)) << 4) | (colb & 15));
}

// ---------------------------------------------------------------------------
// KT: x [B][CIN][N] f32  ->  xT [B][N][CIN] bf16   (LDS 64x64 tile transpose)
// ---------------------------------------------------------------------------
__global__ __launch_bounds__(256) void kt_transpose(const float* __restrict__ x,
                                                    bf16* __restrict__ xT) {
    __shared__ float tile[64][65];
    int n0 = blockIdx.x * 64, c0 = blockIdx.y * 64, b = blockIdx.z;
    const float* xp = x + (size_t)b * CIN * NPOS;
    int t = threadIdx.x;
    int lr = t >> 4;            // 0..15
    int lc4 = (t & 15) * 4;     // 0..60
    for (int p = 0; p < 4; ++p) {
        int c = lr + p * 16;
        f32x4 v = *reinterpret_cast<const f32x4*>(xp + (size_t)(c0 + c) * NPOS + n0 + lc4);
        tile[c][lc4 + 0] = v[0]; tile[c][lc4 + 1] = v[1];
        tile[c][lc4 + 2] = v[2]; tile[c][lc4 + 3] = v[3];
    }
    __syncthreads();
    bf16* xtp = xT + (size_t)b * NPOS * CIN;
    int cc = (t & 15) * 4;
    for (int p = 0; p < 4; ++p) {
        int n = (t >> 4) + p * 16;
        bf16x4 o;
        o[0] = (bf16)tile[cc + 0][n]; o[1] = (bf16)tile[cc + 1][n];
        o[2] = (bf16)tile[cc + 2][n]; o[3] = (bf16)tile[cc + 3][n];
        *reinterpret_cast<bf16x4*>(xtp + (size_t)(n0 + n) * CIN + c0 + cc) = o;
    }
}

// ---------------------------------------------------------------------------
// K1: q/k/v = W @ x + b.  grid (32 ntile, 3 which, B).
// Output: qT,kT [B][N][128] bf16 (pos-major), vC [B][128][N] bf16 (ch-major).
// ---------------------------------------------------------------------------
__global__ __launch_bounds__(256) void k_qkv(
    const float* __restrict__ Wq, const float* __restrict__ Wk, const float* __restrict__ Wv,
    const float* __restrict__ bq, const float* __restrict__ bk, const float* __restrict__ bv,
    const bf16* __restrict__ xT, bf16* __restrict__ qT, bf16* __restrict__ kT,
    bf16* __restrict__ vC) {
    __shared__ __align__(16) char a_lds[128 * 128];  // [128 o][64 k] bf16 swz
    __shared__ __align__(16) char b_lds[128 * 128];  // [128 n][64 k] bf16 swz
    int n0 = blockIdx.x * 128, which = blockIdx.y, b = blockIdx.z;
    const float* W    = which == 0 ? Wq : (which == 1 ? Wk : Wv);
    const float* bias = which == 0 ? bq : (which == 1 ? bk : bv);
    int t = threadIdx.x, lane = t & 63, w = t >> 6, wy = w >> 1, wx = w & 1;
    const bf16* xb = xT + (size_t)b * NPOS * CIN;

    f32x4 acc[4][4] = {};
    for (int k0 = 0; k0 < 256; k0 += 64) {
        __syncthreads();
        for (int i = 0; i < 8; ++i) {                 // A: W f32 -> bf16
            int idx = t + i * 256;                    // 2048 float4
            int row = idx >> 4, c4 = (idx & 15) * 4;
            f32x4 v = *reinterpret_cast<const f32x4*>(W + (size_t)row * CIN + k0 + c4);
            bf16x4 o; o[0] = (bf16)v[0]; o[1] = (bf16)v[1]; o[2] = (bf16)v[2]; o[3] = (bf16)v[3];
            *reinterpret_cast<bf16x4*>(a_lds + swz128(row, c4 * 2)) = o;
        }
        for (int i = 0; i < 4; ++i) {                 // B: xT bf16 copy
            int idx = t + i * 256;                    // 1024 16B chunks
            int row = idx >> 3, cb = (idx & 7) * 16;
            bf16x8 vv = *reinterpret_cast<const bf16x8*>(xb + (size_t)(n0 + row) * CIN + k0 + cb / 2);
            *reinterpret_cast<bf16x8*>(b_lds + swz128(row, cb)) = vv;
        }
        __syncthreads();
        for (int ks = 0; ks < 2; ++ks) {
            int kb = ks * 64 + (lane >> 4) * 16;
            bf16x8 af[4], bfr[4];
            for (int i = 0; i < 4; ++i)
                af[i] = *reinterpret_cast<const bf16x8*>(a_lds + swz128(wy * 64 + i * 16 + (lane & 15), kb));
            for (int j = 0; j < 4; ++j)
                bfr[j] = *reinterpret_cast<const bf16x8*>(b_lds + swz128(wx * 64 + j * 16 + (lane & 15), kb));
            for (int i = 0; i < 4; ++i)
                for (int j = 0; j < 4; ++j)
                    acc[i][j] = MFMA16(af[i], bfr[j], acc[i][j]);
        }
    }
    int rg = lane >> 4, cl = lane & 15;
    for (int i = 0; i < 4; ++i) {
        int ch0 = wy * 64 + i * 16 + rg * 4;
        f32x4 bv4 = *reinterpret_cast<const f32x4*>(bias + ch0);
        for (int j = 0; j < 4; ++j) {
            int n = n0 + wx * 64 + j * 16 + cl;
            f32x4 d = acc[i][j];
            for (int r = 0; r < 4; ++r) d[r] += bv4[r];
            if (which == 2) {
                for (int r = 0; r < 4; ++r)
                    vC[((size_t)b * CMID + ch0 + r) * NPOS + n] = (bf16)d[r];
            } else {
                bf16x4 o; o[0] = (bf16)d[0]; o[1] = (bf16)d[1]; o[2] = (bf16)d[2]; o[3] = (bf16)d[3];
                bf16* dst = (which == 0 ? qT : kT);
                *reinterpret_cast<bf16x4*>(dst + ((size_t)b * NPOS + n) * CMID + ch0) = o;
            }
        }
    }
}

// ---------------------------------------------------------------------------
// K2: zpart[mq][b][n] = sum_{m in eighth mq} exp(S[n,m]), S[n,m]=k[:,n].q[:,m]
// grid (32 ntile, 8 mq, B). Block owns 128 n (k-frags hoisted to registers),
// steps 8x 64 m (q staged in LDS). S bounded (~±25): no max needed.
// ---------------------------------------------------------------------------
__global__ __launch_bounds__(256, 4) void k_zrow(const bf16* __restrict__ qT,
                                                 const bf16* __restrict__ kT,
                                                 float* __restrict__ zpart) {
    __shared__ __align__(16) char q_lds[64 * 256];  // [64 m][128 c] bf16 swz
    int n0 = blockIdx.x * 128, mq = blockIdx.y, b = blockIdx.z;
    int t = threadIdx.x, lane = t & 63, w = t >> 6;
    int cl = lane & 15, g = lane >> 4;
    const bf16* qb = qT + (size_t)b * NPOS * CMID;
    const bf16* kb = kT + (size_t)b * NPOS * CMID;
    // k fragments (B-operand): wave owns n = n0 + w*32 + jn*16 + cl
    bf16x8 kreg[2][4];
    for (int jn = 0; jn < 2; ++jn)
        for (int ks = 0; ks < 4; ++ks)
            kreg[jn][ks] = *reinterpret_cast<const bf16x8*>(
                kb + (size_t)(n0 + w * 32 + jn * 16 + cl) * CMID + ks * 32 + g * 8);
    float zacc[2] = {0.f, 0.f};
    int mbeg = mq * (NPOS / 8);
    for (int m0 = mbeg; m0 < mbeg + NPOS / 8; m0 += 64) {
        __syncthreads();
        for (int i = 0; i < 4; ++i) {
            int idx = t + i * 256, row = idx >> 4, cb = (idx & 15) * 16;
            bf16x8 vv = *reinterpret_cast<const bf16x8*>(qb + (size_t)(m0 + row) * CMID + cb / 2);
            *reinterpret_cast<bf16x8*>(q_lds + swz256(row, cb)) = vv;
        }
        __syncthreads();
        f32x4 acc[4][2] = {};   // D[m][n]: m-tiles im, n-tiles jn
        for (int ks = 0; ks < 4; ++ks) {
            bf16x8 qf[4];
            for (int im = 0; im < 4; ++im)
                qf[im] = *reinterpret_cast<const bf16x8*>(q_lds + swz256(im * 16 + cl, ks * 64 + g * 16));
            for (int im = 0; im < 4; ++im)
                for (int jn = 0; jn < 2; ++jn)
                    acc[im][jn] = MFMA16(qf[im], kreg[jn][ks], acc[im][jn]);
        }
        for (int im = 0; im < 4; ++im)
            for (int jn = 0; jn < 2; ++jn)
                for (int r = 0; r < 4; ++r)
                    zacc[jn] += __expf(acc[im][jn][r]);
    }
    for (int jn = 0; jn < 2; ++jn) {
        zacc[jn] += __shfl_xor(zacc[jn], 16);
        zacc[jn] += __shfl_xor(zacc[jn], 32);
    }
    if (g == 0) {
        float* zp = zpart + ((size_t)mq * BATCH + b) * NPOS;
        zp[n0 + w * 32 + cl]      = zacc[0];
        zp[n0 + w * 32 + 16 + cl] = zacc[1];
    }
}

// ---------------------------------------------------------------------------
// K3: invZ = 1 / sum_{s<8} zpart[s].   16384 elems, f32x4.
// ---------------------------------------------------------------------------
__global__ __launch_bounds__(256) void k_rcp(const float* __restrict__ zpart,
                                             float* __restrict__ invZ) {
    int i = (blockIdx.x * 256 + threadIdx.x) * 4;
    f32x4 s = {0.f, 0.f, 0.f, 0.f};
    for (int p = 0; p < 8; ++p) {
        f32x4 a = *reinterpret_cast<const f32x4*>(zpart + (size_t)p * BATCH * NPOS + i);
        for (int r = 0; r < 4; ++r) s[r] += a[r];
    }
    f32x4 o;
    for (int r = 0; r < 4; ++r) o[r] = 1.f / s[r];
    *reinterpret_cast<f32x4*>(invZ + i) = o;
}

// ---------------------------------------------------------------------------
// K4: y[m][c] = sum_n P[n,m] v[c,n],  P = exp(S)*invZ[n]  (P in (0,1]).
// grid (32 mtile(128), 4 nq, B) = 512 blocks, 2/CU.  q-fragments hoisted to
// registers (loaded once); LDS = k(16K)+v(16K)+P(16K)=48KB.  Partial y in
// bf16, one slice per n-quarter, summed in k_out.
// ---------------------------------------------------------------------------
__global__ __launch_bounds__(256, 2) void k_attn(const bf16* __restrict__ qT,
                                                 const bf16* __restrict__ kT,
                                                 const bf16* __restrict__ vC,
                                                 const float* __restrict__ invZ,
                                                 bf16* __restrict__ ypA,
                                                 bf16* __restrict__ ypB) {
    __shared__ __align__(16) char k_lds[64 * 256];   // [64 n][128 c] swz256
    __shared__ __align__(16) char v_lds[128 * 128];  // [128 c][64 n] swz128
    __shared__ __align__(16) char p_lds[128 * 128];  // [128 m][64 n] swz128
    int m0 = blockIdx.x * 128, nq = blockIdx.y, b = blockIdx.z;
    int t = threadIdx.x, lane = t & 63, w = t >> 6;
    int cl = lane & 15, g = lane >> 4;
    const bf16* qb = qT + (size_t)b * NPOS * CMID;
    const bf16* kb = kT + (size_t)b * NPOS * CMID;
    const bf16* vb = vC + (size_t)b * CMID * NPOS;
    const float* izb = invZ + (size_t)b * NPOS;
    // q fragments (B-operand): wave owns m-cols m0 + w*32 + jm*16 + cl
    bf16x8 qreg[2][4];
    for (int jm = 0; jm < 2; ++jm)
        for (int ks = 0; ks < 4; ++ks)
            qreg[jm][ks] = *reinterpret_cast<const bf16x8*>(
                qb + (size_t)(m0 + w * 32 + jm * 16 + cl) * CMID + ks * 32 + g * 8);

    f32x4 acc2[8][2] = {};                           // y[m 128][c: w*32 + 2 tiles]
    int nbeg = nq * (NPOS / 4);
    for (int n0 = nbeg; n0 < nbeg + NPOS / 4; n0 += 64) {
        __syncthreads();
        for (int i = 0; i < 4; ++i) {                // stage k-tile [64n][128c]
            int idx = t + i * 256, row = idx >> 4, cb = (idx & 15) * 16;
            bf16x8 vv = *reinterpret_cast<const bf16x8*>(kb + (size_t)(n0 + row) * CMID + cb / 2);
            *reinterpret_cast<bf16x8*>(k_lds + swz256(row, cb)) = vv;
        }
        for (int i = 0; i < 4; ++i) {                // stage v-tile [128c][64n]
            int idx = t + i * 256, row = idx >> 3, cb = (idx & 7) * 16;
            bf16x8 vv = *reinterpret_cast<const bf16x8*>(vb + (size_t)row * NPOS + n0 + cb / 2);
            *reinterpret_cast<bf16x8*>(v_lds + swz128(row, cb)) = vv;
        }
        __syncthreads();
        // S^T: acc1[in][jm] = D[n=in*16+g*4+r][m = w*32+jm*16+cl]
        f32x4 acc1[4][2] = {};
        for (int ks = 0; ks < 4; ++ks) {
            bf16x8 kf[4];
            for (int in = 0; in < 4; ++in)
                kf[in] = *reinterpret_cast<const bf16x8*>(k_lds + swz256(in * 16 + cl, ks * 64 + g * 16));
            for (int in = 0; in < 4; ++in)
                for (int jm = 0; jm < 2; ++jm)
                    acc1[in][jm] = MFMA16(kf[in], qreg[jm][ks], acc1[in][jm]);
        }
        // P^T[m][n] = exp(S)*invZ[n]; lane writes 4 consecutive n (8B).
        for (int in = 0; in < 4; ++in) {
            f32x4 iz = *reinterpret_cast<const f32x4*>(izb + n0 + in * 16 + g * 4);
            for (int jm = 0; jm < 2; ++jm) {
                bf16x4 o;
                for (int r = 0; r < 4; ++r) o[r] = (bf16)(__expf(acc1[in][jm][r]) * iz[r]);
                *reinterpret_cast<bf16x4*>(p_lds + swz128(w * 32 + jm * 16 + cl, in * 32 + g * 8)) = o;
            }
        }
        __syncthreads();
        for (int ks = 0; ks < 2; ++ks) {             // PV: all m, wave's 32 c
            bf16x8 af[8], vf[2];
            for (int i = 0; i < 8; ++i)
                af[i] = *reinterpret_cast<const bf16x8*>(p_lds + swz128(i * 16 + cl, ks * 64 + g * 16));
            for (int j = 0; j < 2; ++j)
                vf[j] = *reinterpret_cast<const bf16x8*>(v_lds + swz128(w * 32 + j * 16 + cl, ks * 64 + g * 16));
            for (int i = 0; i < 8; ++i)
                for (int j = 0; j < 2; ++j)
                    acc2[i][j] = MFMA16(af[i], vf[j], acc2[i][j]);
        }
    }
    bf16* yb = ((nq & 2) ? ypB : ypA) + ((size_t)(nq & 1) * BATCH + b) * NPOS * CMID
             + (size_t)m0 * CMID;
    for (int i = 0; i < 8; ++i)
        for (int j = 0; j < 2; ++j) {
            int c = w * 32 + j * 16 + cl;
            for (int r = 0; r < 4; ++r) {
                int m = i * 16 + g * 4 + r;
                yb[(size_t)m * CMID + c] = (bf16)acc2[i][j][r];
            }
        }
}

// ---------------------------------------------------------------------------
// K5: out = (Ww @ sum(y-slices) + bw)*inv + add + x. grid (32 mtile,2 otile,B).
// ---------------------------------------------------------------------------
__global__ __launch_bounds__(256) void k_out(
    const float* __restrict__ Ww, const float* __restrict__ bw,
    const float* __restrict__ gamma, const float* __restrict__ beta,
    const float* __restrict__ mean, const float* __restrict__ var,
    const bf16* __restrict__ ypA, const bf16* __restrict__ ypB,
    const float* __restrict__ x, float* __restrict__ out) {
    __shared__ __align__(16) char a_lds[128 * 128];  // [128 o][64 c] bf16 swz
    __shared__ __align__(16) char b_lds[128 * 128];  // [128 m][64 c] bf16 swz
    int m0 = blockIdx.x * 128, o0 = blockIdx.y * 128, b = blockIdx.z;
    int t = threadIdx.x, lane = t & 63, w = t >> 6, wy = w >> 1, wx = w & 1;
    size_t boff = (size_t)b * NPOS * CMID;
    const bf16* y0 = ypA + boff;
    const bf16* y1 = ypA + (size_t)BATCH * NPOS * CMID + boff;
    const bf16* y2 = ypB + boff;
    const bf16* y3 = ypB + (size_t)BATCH * NPOS * CMID + boff;
    f32x4 acc[4][4] = {};
    for (int k0 = 0; k0 < 128; k0 += 64) {
        __syncthreads();
        for (int i = 0; i < 8; ++i) {
            int idx = t + i * 256, row = idx >> 4, c4 = (idx & 15) * 4;
            f32x4 v = *reinterpret_cast<const f32x4*>(Ww + (size_t)(o0 + row) * CMID + k0 + c4);
            bf16x4 o; o[0] = (bf16)v[0]; o[1] = (bf16)v[1]; o[2] = (bf16)v[2]; o[3] = (bf16)v[3];
            *reinterpret_cast<bf16x4*>(a_lds + swz128(row, c4 * 2)) = o;
        }
        for (int i = 0; i < 8; ++i) {
            int idx = t + i * 256, row = idx >> 4, c4 = (idx & 15) * 4;
            size_t yoff = (size_t)(m0 + row) * CMID + k0 + c4;
            bf16x4 a0 = *reinterpret_cast<const bf16x4*>(y0 + yoff);
            bf16x4 a1 = *reinterpret_cast<const bf16x4*>(y1 + yoff);
            bf16x4 a2 = *reinterpret_cast<const bf16x4*>(y2 + yoff);
            bf16x4 a3 = *reinterpret_cast<const bf16x4*>(y3 + yoff);
            bf16x4 o;
            for (int r = 0; r < 4; ++r)
                o[r] = (bf16)((float)a0[r] + (float)a1[r] + (float)a2[r] + (float)a3[r]);
            *reinterpret_cast<bf16x4*>(b_lds + swz128(row, c4 * 2)) = o;
        }
        __syncthreads();
        for (int ks = 0; ks < 2; ++ks) {
            int kb = ks * 64 + (lane >> 4) * 16;
            bf16x8 af[4], bfr[4];
            for (int i = 0; i < 4; ++i)
                af[i] = *reinterpret_cast<const bf16x8*>(a_lds + swz128(wy * 64 + i * 16 + (lane & 15), kb));
            for (int j = 0; j < 4; ++j)
                bfr[j] = *reinterpret_cast<const bf16x8*>(b_lds + swz128(wx * 64 + j * 16 + (lane & 15), kb));
            for (int i = 0; i < 4; ++i)
                for (int j = 0; j < 4; ++j)
                    acc[i][j] = MFMA16(af[i], bfr[j], acc[i][j]);
        }
    }
    int rg = lane >> 4, cl = lane & 15;
    const float* xb = x + (size_t)b * CIN * NPOS;
    float* ob = out + (size_t)b * CIN * NPOS;
    for (int i = 0; i < 4; ++i) {
        int och0 = o0 + wy * 64 + i * 16 + rg * 4;
        f32x4 g  = *reinterpret_cast<const f32x4*>(gamma + och0);
        f32x4 be = *reinterpret_cast<const f32x4*>(beta + och0);
        f32x4 mu = *reinterpret_cast<const f32x4*>(mean + och0);
        f32x4 va = *reinterpret_cast<const f32x4*>(var + och0);
        f32x4 bb = *reinterpret_cast<const f32x4*>(bw + och0);
        float invv[4], addv[4];
        for (int r = 0; r < 4; ++r) {
            invv[r] = g[r] / sqrtf(va[r] + EPS);
            addv[r] = be[r] - mu[r] * invv[r];
        }
        for (int j = 0; j < 4; ++j) {
            int m = m0 + wx * 64 + j * 16 + cl;
            for (int r = 0; r < 4; ++r) {
                float z = (acc[i][j][r] + bb[r]) * invv[r] + addv[r];
                ob[(size_t)(och0 + r) * NPOS + m] = z + xb[(size_t)(och0 + r) * NPOS + m];
            }
        }
    }
}

// ---------------------------------------------------------------------------
extern "C" void kernel_launch(void* const* d_in, const int* in_sizes, int n_in,
                              void* d_out, int out_size, void* d_ws, size_t ws_size,
                              hipStream_t stream) {
    const float* x     = (const float*)d_in[0];
    const float* Wq    = (const float*)d_in[1];
    const float* bq    = (const float*)d_in[2];
    const float* Wk    = (const float*)d_in[3];
    const float* bk    = (const float*)d_in[4];
    const float* Wv    = (const float*)d_in[5];
    const float* bv    = (const float*)d_in[6];
    const float* Ww    = (const float*)d_in[7];
    const float* bw    = (const float*)d_in[8];
    const float* gamma = (const float*)d_in[9];
    const float* beta  = (const float*)d_in[10];
    const float* mean  = (const float*)d_in[11];
    const float* var   = (const float*)d_in[12];
    float* out = (float*)d_out;

    char* ws = (char*)d_ws;
    // Region A (8MB): xT during kt/k_qkv, then reused as ypA (2 bf16 y-slices).
    char* regionA = ws;                    ws += (size_t)BATCH * NPOS * CIN * 2;   // 8 MB
    bf16* qT = (bf16*)ws;                  ws += (size_t)BATCH * NPOS * CMID * 2;  // 4 MB
    bf16* kT = (bf16*)ws;                  ws += (size_t)BATCH * NPOS * CMID * 2;  // 4 MB
    bf16* vC = (bf16*)ws;                  ws += (size_t)BATCH * NPOS * CMID * 2;  // 4 MB
    bf16* ypB = (bf16*)ws;                 ws += (size_t)2 * BATCH * NPOS * CMID * 2; // 8 MB
    float* zpart = (float*)ws;             ws += (size_t)8 * BATCH * NPOS * 4;     // 512 KB
    float* invZ = (float*)ws;                                                     // 64 KB
    bf16* xT  = (bf16*)regionA;
    bf16* ypA = (bf16*)regionA;            // valid once k_qkv no longer needs xT

    kt_transpose<<<dim3(NPOS / 64, CIN / 64, BATCH), 256, 0, stream>>>(x, xT);
    k_qkv<<<dim3(NPOS / 128, 3, BATCH), 256, 0, stream>>>(Wq, Wk, Wv, bq, bk, bv, xT, qT, kT, vC);
    k_zrow<<<dim3(NPOS / 128, 8, BATCH), 256, 0, stream>>>(qT, kT, zpart);
    k_rcp<<<dim3(BATCH * NPOS / 1024), 256, 0, stream>>>(zpart, invZ);
    k_attn<<<dim3(NPOS / 128, 4, BATCH), 256, 0, stream>>>(qT, kT, vC, invZ, ypA, ypB);
    k_out<<<dim3(NPOS / 128, 2, BATCH), 256, 0, stream>>>(Ww, bw, gamma, beta, mean, var, ypA, ypB, x, out);
}

// Round 5
// 101.350 us; speedup vs baseline: 1.9365x; 1.0000x over previous
//
#include <hip/hip_runtime.h>
#include <hip/hip_bf16.h>

#define BATCH 4
#define CIN   256
#define CMID  128
#define NPOS  4096
#define EPS   1e-5f

typedef __bf16 bf16;
typedef __attribute__((ext_vector_type(8))) __bf16 bf16x8;
typedef __attribute__((ext_vector_type(4))) __bf16 bf16x4;
typedef __attribute__((ext_vector_type(4))) float  f32x4;

#define MFMA16(a, b, c) __builtin_amdgcn_mfma_f32_16x16x32_bf16((a), (b), (c), 0, 0, 0)

// async global->LDS DMA, 16B per lane, dest = wave-uniform base + lane*16
#define GLDS(gsrc, ldst) \
    __builtin_amdgcn_global_load_lds( \
        (const __attribute__((address_space(1))) void*)(gsrc), \
        (__attribute__((address_space(3))) void*)(ldst), 16, 0, 0)

// XOR swizzle: 16B chunks within a row, chunk ^= (row & 7). Bijective, kills
// the bank conflicts of row-major bf16 tiles read 16-rows-at-a-time.
// DMA staging writes LDS linearly; the global SOURCE is pre-swizzled with the
// same involution so swizzled reads see the right data (both-sides rule).
__device__ __forceinline__ int swz128(int row, int colb) {
    return row * 128 + ((((colb >> 4) ^ (row & 7)) << 4) | (colb & 15));
}
__device__ __forceinline__ int swz256(int row, int colb) {
    return row * 256 + ((((colb >> 4) ^ (row & 7)) << 4) | (colb & 15));
}

// ---------------------------------------------------------------------------
// KT: x [B][CIN][N] f32  ->  xT [B][N][CIN] bf16   (LDS 64x64 tile transpose)
// ---------------------------------------------------------------------------
__global__ __launch_bounds__(256) void kt_transpose(const float* __restrict__ x,
                                                    bf16* __restrict__ xT) {
    __shared__ float tile[64][65];
    int n0 = blockIdx.x * 64, c0 = blockIdx.y * 64, b = blockIdx.z;
    const float* xp = x + (size_t)b * CIN * NPOS;
    int t = threadIdx.x;
    int lr = t >> 4;            // 0..15
    int lc4 = (t & 15) * 4;     // 0..60
    for (int p = 0; p < 4; ++p) {
        int c = lr + p * 16;
        f32x4 v = *reinterpret_cast<const f32x4*>(xp + (size_t)(c0 + c) * NPOS + n0 + lc4);
        tile[c][lc4 + 0] = v[0]; tile[c][lc4 + 1] = v[1];
        tile[c][lc4 + 2] = v[2]; tile[c][lc4 + 3] = v[3];
    }
    __syncthreads();
    bf16* xtp = xT + (size_t)b * NPOS * CIN;
    int cc = (t & 15) * 4;
    for (int p = 0; p < 4; ++p) {
        int n = (t >> 4) + p * 16;
        bf16x4 o;
        o[0] = (bf16)tile[cc + 0][n]; o[1] = (bf16)tile[cc + 1][n];
        o[2] = (bf16)tile[cc + 2][n]; o[3] = (bf16)tile[cc + 3][n];
        *reinterpret_cast<bf16x4*>(xtp + (size_t)(n0 + n) * CIN + c0 + cc) = o;
    }
}

// ---------------------------------------------------------------------------
// K1: q/k/v = W @ x + b.  grid (32 ntile, 3 which, B).
// Output: qT,kT [B][N][128] bf16 (pos-major), vC [B][128][N] bf16 (ch-major).
// ---------------------------------------------------------------------------
__global__ __launch_bounds__(256) void k_qkv(
    const float* __restrict__ Wq, const float* __restrict__ Wk, const float* __restrict__ Wv,
    const float* __restrict__ bq, const float* __restrict__ bk, const float* __restrict__ bv,
    const bf16* __restrict__ xT, bf16* __restrict__ qT, bf16* __restrict__ kT,
    bf16* __restrict__ vC) {
    __shared__ __align__(16) char a_lds[128 * 128];  // [128 o][64 k] bf16 swz
    __shared__ __align__(16) char b_lds[128 * 128];  // [128 n][64 k] bf16 swz
    int n0 = blockIdx.x * 128, which = blockIdx.y, b = blockIdx.z;
    const float* W    = which == 0 ? Wq : (which == 1 ? Wk : Wv);
    const float* bias = which == 0 ? bq : (which == 1 ? bk : bv);
    int t = threadIdx.x, lane = t & 63, w = t >> 6, wy = w >> 1, wx = w & 1;
    const bf16* xb = xT + (size_t)b * NPOS * CIN;

    f32x4 acc[4][4] = {};
    for (int k0 = 0; k0 < 256; k0 += 64) {
        __syncthreads();
        for (int i = 0; i < 8; ++i) {                 // A: W f32 -> bf16
            int idx = t + i * 256;                    // 2048 float4
            int row = idx >> 4, c4 = (idx & 15) * 4;
            f32x4 v = *reinterpret_cast<const f32x4*>(W + (size_t)row * CIN + k0 + c4);
            bf16x4 o; o[0] = (bf16)v[0]; o[1] = (bf16)v[1]; o[2] = (bf16)v[2]; o[3] = (bf16)v[3];
            *reinterpret_cast<bf16x4*>(a_lds + swz128(row, c4 * 2)) = o;
        }
        for (int i = 0; i < 4; ++i) {                 // B: xT bf16 copy
            int idx = t + i * 256;                    // 1024 16B chunks
            int row = idx >> 3, cb = (idx & 7) * 16;
            bf16x8 vv = *reinterpret_cast<const bf16x8*>(xb + (size_t)(n0 + row) * CIN + k0 + cb / 2);
            *reinterpret_cast<bf16x8*>(b_lds + swz128(row, cb)) = vv;
        }
        __syncthreads();
        for (int ks = 0; ks < 2; ++ks) {
            int kb = ks * 64 + (lane >> 4) * 16;
            bf16x8 af[4], bfr[4];
            for (int i = 0; i < 4; ++i)
                af[i] = *reinterpret_cast<const bf16x8*>(a_lds + swz128(wy * 64 + i * 16 + (lane & 15), kb));
            for (int j = 0; j < 4; ++j)
                bfr[j] = *reinterpret_cast<const bf16x8*>(b_lds + swz128(wx * 64 + j * 16 + (lane & 15), kb));
            for (int i = 0; i < 4; ++i)
                for (int j = 0; j < 4; ++j)
                    acc[i][j] = MFMA16(af[i], bfr[j], acc[i][j]);
        }
    }
    int rg = lane >> 4, cl = lane & 15;
    for (int i = 0; i < 4; ++i) {
        int ch0 = wy * 64 + i * 16 + rg * 4;
        f32x4 bv4 = *reinterpret_cast<const f32x4*>(bias + ch0);
        for (int j = 0; j < 4; ++j) {
            int n = n0 + wx * 64 + j * 16 + cl;
            f32x4 d = acc[i][j];
            for (int r = 0; r < 4; ++r) d[r] += bv4[r];
            if (which == 2) {
                for (int r = 0; r < 4; ++r)
                    vC[((size_t)b * CMID + ch0 + r) * NPOS + n] = (bf16)d[r];
            } else {
                bf16x4 o; o[0] = (bf16)d[0]; o[1] = (bf16)d[1]; o[2] = (bf16)d[2]; o[3] = (bf16)d[3];
                bf16* dst = (which == 0 ? qT : kT);
                *reinterpret_cast<bf16x4*>(dst + ((size_t)b * NPOS + n) * CMID + ch0) = o;
            }
        }
    }
}

// ---------------------------------------------------------------------------
// K2: zpart[mq][b][n] = sum_{m in eighth mq} exp(S[n,m]), S[n,m]=k[:,n].q[:,m]
// grid (32 ntile, 8 mq, B). k-frags in registers; q staged via async DMA into
// double-buffered LDS, prefetch issued before compute, 1 barrier/step.
// ---------------------------------------------------------------------------
__global__ __launch_bounds__(256, 4) void k_zrow(const bf16* __restrict__ qT,
                                                 const bf16* __restrict__ kT,
                                                 float* __restrict__ zpart) {
    __shared__ __align__(16) char q_lds[2][64 * 256];  // [64 m][128 c] bf16 swz
    int n0 = blockIdx.x * 128, mq = blockIdx.y, b = blockIdx.z;
    int t = threadIdx.x, lane = t & 63, w = t >> 6;
    int cl = lane & 15, g = lane >> 4;
    const bf16* qb = qT + (size_t)b * NPOS * CMID;
    const bf16* kb = kT + (size_t)b * NPOS * CMID;

    auto stage_q = [&](int buf, int m0) {
        #pragma unroll
        for (int i = 0; i < 4; ++i) {
            int lc = (w * 4 + i) * 64 + lane;        // 16B-chunk idx in tile
            int r = lc >> 4, p = lc & 15;
            GLDS(qb + (size_t)(m0 + r) * CMID + ((p ^ (r & 7)) << 3),
                 q_lds[buf] + (w * 4 + i) * 1024);
        }
    };

    // k fragments (B-operand): wave owns n = n0 + w*32 + jn*16 + cl
    bf16x8 kreg[2][4];
    for (int jn = 0; jn < 2; ++jn)
        for (int ks = 0; ks < 4; ++ks)
            kreg[jn][ks] = *reinterpret_cast<const bf16x8*>(
                kb + (size_t)(n0 + w * 32 + jn * 16 + cl) * CMID + ks * 32 + g * 8);

    int mbeg = mq * (NPOS / 8);
    stage_q(0, mbeg);
    asm volatile("s_waitcnt vmcnt(0)" ::: "memory");
    __syncthreads();
    int cur = 0;
    float zacc[2] = {0.f, 0.f};
    for (int m0 = mbeg; m0 < mbeg + NPOS / 8; m0 += 64) {
        if (m0 + 64 < mbeg + NPOS / 8) stage_q(cur ^ 1, m0 + 64);
        f32x4 acc[4][2] = {};   // D[m][n]: m-tiles im, n-tiles jn
        for (int ks = 0; ks < 4; ++ks) {
            bf16x8 qf[4];
            for (int im = 0; im < 4; ++im)
                qf[im] = *reinterpret_cast<const bf16x8*>(q_lds[cur] + swz256(im * 16 + cl, ks * 64 + g * 16));
            for (int im = 0; im < 4; ++im)
                for (int jn = 0; jn < 2; ++jn)
                    acc[im][jn] = MFMA16(qf[im], kreg[jn][ks], acc[im][jn]);
        }
        for (int im = 0; im < 4; ++im)
            for (int jn = 0; jn < 2; ++jn)
                for (int r = 0; r < 4; ++r)
                    zacc[jn] += __expf(acc[im][jn][r]);
        __syncthreads();        // drains lgkm (reads of cur) + vmcnt (buf cur^1)
        cur ^= 1;
    }
    for (int jn = 0; jn < 2; ++jn) {
        zacc[jn] += __shfl_xor(zacc[jn], 16);
        zacc[jn] += __shfl_xor(zacc[jn], 32);
    }
    if (g == 0) {
        float* zp = zpart + ((size_t)mq * BATCH + b) * NPOS;
        zp[n0 + w * 32 + cl]      = zacc[0];
        zp[n0 + w * 32 + 16 + cl] = zacc[1];
    }
}

// ---------------------------------------------------------------------------
// K3: invZ = 1 / sum_{s<8} zpart[s].   16384 elems, f32x4.
// ---------------------------------------------------------------------------
__global__ __launch_bounds__(256) void k_rcp(const float* __restrict__ zpart,
                                             float* __restrict__ invZ) {
    int i = (blockIdx.x * 256 + threadIdx.x) * 4;
    f32x4 s = {0.f, 0.f, 0.f, 0.f};
    for (int p = 0; p < 8; ++p) {
        f32x4 a = *reinterpret_cast<const f32x4*>(zpart + (size_t)p * BATCH * NPOS + i);
        for (int r = 0; r < 4; ++r) s[r] += a[r];
    }
    f32x4 o;
    for (int r = 0; r < 4; ++r) o[r] = 1.f / s[r];
    *reinterpret_cast<f32x4*>(invZ + i) = o;
}

// ---------------------------------------------------------------------------
// K4: y[m][c] = sum_n P[n,m] v[c,n],  P = exp(S)*invZ[n]  (P in (0,1]).
// grid (32 mtile(128), 4 nq, B) = 512 blocks, 2/CU.  q-frags in registers;
// k/v staged via async DMA into double-buffered LDS, prefetch issued before
// the S-GEMM so load latency hides under compute. LDS 80KB.
// ---------------------------------------------------------------------------
__global__ __launch_bounds__(256, 2) void k_attn(const bf16* __restrict__ qT,
                                                 const bf16* __restrict__ kT,
                                                 const bf16* __restrict__ vC,
                                                 const float* __restrict__ invZ,
                                                 bf16* __restrict__ ypA,
                                                 bf16* __restrict__ ypB) {
    __shared__ __align__(16) char k_lds[2][64 * 256];   // [64 n][128 c] swz256
    __shared__ __align__(16) char v_lds[2][128 * 128];  // [128 c][64 n] swz128
    __shared__ __align__(16) char p_lds[128 * 128];     // [128 m][64 n] swz128
    int m0 = blockIdx.x * 128, nq = blockIdx.y, b = blockIdx.z;
    int t = threadIdx.x, lane = t & 63, w = t >> 6;
    int cl = lane & 15, g = lane >> 4;
    const bf16* qb = qT + (size_t)b * NPOS * CMID;
    const bf16* kb = kT + (size_t)b * NPOS * CMID;
    const bf16* vb = vC + (size_t)b * CMID * NPOS;
    const float* izb = invZ + (size_t)b * NPOS;

    auto stage_kv = [&](int buf, int n0) {
        #pragma unroll
        for (int i = 0; i < 4; ++i) {
            int lc = (w * 4 + i) * 64 + lane;        // 16B-chunk idx in tile
            int kr = lc >> 4, kp = lc & 15;          // k: 16 chunks per row
            GLDS(kb + (size_t)(n0 + kr) * CMID + ((kp ^ (kr & 7)) << 3),
                 k_lds[buf] + (w * 4 + i) * 1024);
            int vr = lc >> 3, vp = lc & 7;           // v: 8 chunks per row
            GLDS(vb + (size_t)vr * NPOS + n0 + ((vp ^ (vr & 7)) << 3),
                 v_lds[buf] + (w * 4 + i) * 1024);
        }
    };

    // q fragments (B-operand): wave owns m-cols m0 + w*32 + jm*16 + cl
    bf16x8 qreg[2][4];
    for (int jm = 0; jm < 2; ++jm)
        for (int ks = 0; ks < 4; ++ks)
            qreg[jm][ks] = *reinterpret_cast<const bf16x8*>(
                qb + (size_t)(m0 + w * 32 + jm * 16 + cl) * CMID + ks * 32 + g * 8);

    f32x4 acc2[8][2] = {};                           // y[m 128][c: w*32 + 2 tiles]
    int nbeg = nq * (NPOS / 4);
    stage_kv(0, nbeg);
    asm volatile("s_waitcnt vmcnt(0)" ::: "memory");
    __syncthreads();
    int cur = 0;
    for (int s = 0; s < NPOS / 4 / 64; ++s) {
        int n0 = nbeg + s * 64;
        if (s + 1 < NPOS / 4 / 64) stage_kv(cur ^ 1, n0 + 64);
        f32x4 iz[4];
        for (int in = 0; in < 4; ++in)
            iz[in] = *reinterpret_cast<const f32x4*>(izb + n0 + in * 16 + g * 4);
        // S^T: acc1[in][jm] = D[n=in*16+g*4+r][m = w*32+jm*16+cl]
        f32x4 acc1[4][2] = {};
        for (int ks = 0; ks < 4; ++ks) {
            bf16x8 kf[4];
            for (int in = 0; in < 4; ++in)
                kf[in] = *reinterpret_cast<const bf16x8*>(k_lds[cur] + swz256(in * 16 + cl, ks * 64 + g * 16));
            for (int in = 0; in < 4; ++in)
                for (int jm = 0; jm < 2; ++jm)
                    acc1[in][jm] = MFMA16(kf[in], qreg[jm][ks], acc1[in][jm]);
        }
        // P^T[m][n] = exp(S)*invZ[n]; lane writes 4 consecutive n (8B).
        for (int in = 0; in < 4; ++in)
            for (int jm = 0; jm < 2; ++jm) {
                bf16x4 o;
                for (int r = 0; r < 4; ++r) o[r] = (bf16)(__expf(acc1[in][jm][r]) * iz[in][r]);
                *reinterpret_cast<bf16x4*>(p_lds + swz128(w * 32 + jm * 16 + cl, in * 32 + g * 8)) = o;
            }
        __syncthreads();        // P visible to all; prefetch drained (vm+lgkm)
        for (int ks = 0; ks < 2; ++ks) {             // PV: all m, wave's 32 c
            bf16x8 af[8], vf[2];
            for (int i = 0; i < 8; ++i)
                af[i] = *reinterpret_cast<const bf16x8*>(p_lds + swz128(i * 16 + cl, ks * 64 + g * 16));
            for (int j = 0; j < 2; ++j)
                vf[j] = *reinterpret_cast<const bf16x8*>(v_lds[cur] + swz128(w * 32 + j * 16 + cl, ks * 64 + g * 16));
            for (int i = 0; i < 8; ++i)
                for (int j = 0; j < 2; ++j)
                    acc2[i][j] = MFMA16(af[i], vf[j], acc2[i][j]);
        }
        __syncthreads();        // PV reads done before next P-write / re-stage
        cur ^= 1;
    }
    bf16* yb = ((nq & 2) ? ypB : ypA) + ((size_t)(nq & 1) * BATCH + b) * NPOS * CMID
             + (size_t)m0 * CMID;
    for (int i = 0; i < 8; ++i)
        for (int j = 0; j < 2; ++j) {
            int c = w * 32 + j * 16 + cl;
            for (int r = 0; r < 4; ++r) {
                int m = i * 16 + g * 4 + r;
                yb[(size_t)m * CMID + c] = (bf16)acc2[i][j][r];
            }
        }
}

// ---------------------------------------------------------------------------
// K5: out = (Ww @ sum(y-slices) + bw)*inv + add + x. grid (32 mtile,2 otile,B).
// ---------------------------------------------------------------------------
__global__ __launch_bounds__(256) void k_out(
    const float* __restrict__ Ww, const float* __restrict__ bw,
    const float* __restrict__ gamma, const float* __restrict__ beta,
    const float* __restrict__ mean, const float* __restrict__ var,
    const bf16* __restrict__ ypA, const bf16* __restrict__ ypB,
    const float* __restrict__ x, float* __restrict__ out) {
    __shared__ __align__(16) char a_lds[128 * 128];  // [128 o][64 c] bf16 swz
    __shared__ __align__(16) char b_lds[128 * 128];  // [128 m][64 c] bf16 swz
    int m0 = blockIdx.x * 128, o0 = blockIdx.y * 128, b = blockIdx.z;
    int t = threadIdx.x, lane = t & 63, w = t >> 6, wy = w >> 1, wx = w & 1;
    size_t boff = (size_t)b * NPOS * CMID;
    const bf16* y0 = ypA + boff;
    const bf16* y1 = ypA + (size_t)BATCH * NPOS * CMID + boff;
    const bf16* y2 = ypB + boff;
    const bf16* y3 = ypB + (size_t)BATCH * NPOS * CMID + boff;
    f32x4 acc[4][4] = {};
    for (int k0 = 0; k0 < 128; k0 += 64) {
        __syncthreads();
        for (int i = 0; i < 8; ++i) {
            int idx = t + i * 256, row = idx >> 4, c4 = (idx & 15) * 4;
            f32x4 v = *reinterpret_cast<const f32x4*>(Ww + (size_t)(o0 + row) * CMID + k0 + c4);
            bf16x4 o; o[0] = (bf16)v[0]; o[1] = (bf16)v[1]; o[2] = (bf16)v[2]; o[3] = (bf16)v[3];
            *reinterpret_cast<bf16x4*>(a_lds + swz128(row, c4 * 2)) = o;
        }
        for (int i = 0; i < 8; ++i) {
            int idx = t + i * 256, row = idx >> 4, c4 = (idx & 15) * 4;
            size_t yoff = (size_t)(m0 + row) * CMID + k0 + c4;
            bf16x4 a0 = *reinterpret_cast<const bf16x4*>(y0 + yoff);
            bf16x4 a1 = *reinterpret_cast<const bf16x4*>(y1 + yoff);
            bf16x4 a2 = *reinterpret_cast<const bf16x4*>(y2 + yoff);
            bf16x4 a3 = *reinterpret_cast<const bf16x4*>(y3 + yoff);
            bf16x4 o;
            for (int r = 0; r < 4; ++r)
                o[r] = (bf16)((float)a0[r] + (float)a1[r] + (float)a2[r] + (float)a3[r]);
            *reinterpret_cast<bf16x4*>(b_lds + swz128(row, c4 * 2)) = o;
        }
        __syncthreads();
        for (int ks = 0; ks < 2; ++ks) {
            int kb = ks * 64 + (lane >> 4) * 16;
            bf16x8 af[4], bfr[4];
            for (int i = 0; i < 4; ++i)
                af[i] = *reinterpret_cast<const bf16x8*>(a_lds + swz128(wy * 64 + i * 16 + (lane & 15), kb));
            for (int j = 0; j < 4; ++j)
                bfr[j] = *reinterpret_cast<const bf16x8*>(b_lds + swz128(wx * 64 + j * 16 + (lane & 15), kb));
            for (int i = 0; i < 4; ++i)
                for (int j = 0; j < 4; ++j)
                    acc[i][j] = MFMA16(af[i], bfr[j], acc[i][j]);
        }
    }
    int rg = lane >> 4, cl = lane & 15;
    const float* xb = x + (size_t)b * CIN * NPOS;
    float* ob = out + (size_t)b * CIN * NPOS;
    for (int i = 0; i < 4; ++i) {
        int och0 = o0 + wy * 64 + i * 16 + rg * 4;
        f32x4 g  = *reinterpret_cast<const f32x4*>(gamma + och0);
        f32x4 be = *reinterpret_cast<const f32x4*>(beta + och0);
        f32x4 mu = *reinterpret_cast<const f32x4*>(mean + och0);
        f32x4 va = *reinterpret_cast<const f32x4*>(var + och0);
        f32x4 bb = *reinterpret_cast<const f32x4*>(bw + och0);
        float invv[4], addv[4];
        for (int r = 0; r < 4; ++r) {
            invv[r] = g[r] / sqrtf(va[r] + EPS);
            addv[r] = be[r] - mu[r] * invv[r];
        }
        for (int j = 0; j < 4; ++j) {
            int m = m0 + wx * 64 + j * 16 + cl;
            for (int r = 0; r < 4; ++r) {
                float z = (acc[i][j][r] + bb[r]) * invv[r] + addv[r];
                ob[(size_t)(och0 + r) * NPOS + m] = z + xb[(size_t)(och0 + r) * NPOS + m];
            }
        }
    }
}

// ---------------------------------------------------------------------------
extern "C" void kernel_launch(void* const* d_in, const int* in_sizes, int n_in,
                              void* d_out, int out_size, void* d_ws, size_t ws_size,
                              hipStream_t stream) {
    const float* x     = (const float*)d_in[0];
    const float* Wq    = (const float*)d_in[1];
    const float* bq    = (const float*)d_in[2];
    const float* Wk    = (const float*)d_in[3];
    const float* bk    = (const float*)d_in[4];
    const float* Wv    = (const float*)d_in[5];
    const float* bv    = (const float*)d_in[6];
    const float* Ww    = (const float*)d_in[7];
    const float* bw    = (const float*)d_in[8];
    const float* gamma = (const float*)d_in[9];
    const float* beta  = (const float*)d_in[10];
    const float* mean  = (const float*)d_in[11];
    const float* var   = (const float*)d_in[12];
    float* out = (float*)d_out;

    char* ws = (char*)d_ws;
    // Region A (8MB): xT during kt/k_qkv, then reused as ypA (2 bf16 y-slices).
    char* regionA = ws;                    ws += (size_t)BATCH * NPOS * CIN * 2;   // 8 MB
    bf16* qT = (bf16*)ws;                  ws += (size_t)BATCH * NPOS * CMID * 2;  // 4 MB
    bf16* kT = (bf16*)ws;                  ws += (size_t)BATCH * NPOS * CMID * 2;  // 4 MB
    bf16* vC = (bf16*)ws;                  ws += (size_t)BATCH * NPOS * CMID * 2;  // 4 MB
    bf16* ypB = (bf16*)ws;                 ws += (size_t)2 * BATCH * NPOS * CMID * 2; // 8 MB
    float* zpart = (float*)ws;             ws += (size_t)8 * BATCH * NPOS * 4;     // 512 KB
    float* invZ = (float*)ws;                                                     // 64 KB
    bf16* xT  = (bf16*)regionA;
    bf16* ypA = (bf16*)regionA;            // valid once k_qkv no longer needs xT

    kt_transpose<<<dim3(NPOS / 64, CIN / 64, BATCH), 256, 0, stream>>>(x, xT);
    k_qkv<<<dim3(NPOS / 128, 3, BATCH), 256, 0, stream>>>(Wq, Wk, Wv, bq, bk, bv, xT, qT, kT, vC);
    k_zrow<<<dim3(NPOS / 128, 8, BATCH), 256, 0, stream>>>(qT, kT, zpart);
    k_rcp<<<dim3(BATCH * NPOS / 1024), 256, 0, stream>>>(zpart, invZ);
    k_attn<<<dim3(NPOS / 128, 4, BATCH), 256, 0, stream>>>(qT, kT, vC, invZ, ypA, ypB);
    k_out<<<dim3(NPOS / 128, 2, BATCH), 256, 0, stream>>>(Ww, bw, gamma, beta, mean, var, ypA, ypB, x, out);
}

// Round 6
// 99.807 us; speedup vs baseline: 1.9664x; 1.0155x over previous
//
#include <hip/hip_runtime.h>
#include <hip/hip_bf16.h>

#define BATCH 4
#define CIN   256
#define CMID  128
#define NPOS  4096
#define EPS   1e-5f

typedef __bf16 bf16;
typedef __attribute__((ext_vector_type(8))) __bf16 bf16x8;
typedef __attribute__((ext_vector_type(4))) __bf16 bf16x4;
typedef __attribute__((ext_vector_type(4))) float  f32x4;

#define MFMA16(a, b, c) __builtin_amdgcn_mfma_f32_16x16x32_bf16((a), (b), (c), 0, 0, 0)

// async global->LDS DMA, 16B per lane, dest = wave-uniform base + lane*16
#define GLDS(gsrc, ldst) \
    __builtin_amdgcn_global_load_lds( \
        (const __attribute__((address_space(1))) void*)(gsrc), \
        (__attribute__((address_space(3))) void*)(ldst), 16, 0, 0)

// XOR swizzle: 16B chunks within a row, chunk ^= (row & 7). Bijective, kills
// the bank conflicts of row-major bf16 tiles read 16-rows-at-a-time.
// DMA staging writes LDS linearly; the global SOURCE is pre-swizzled with the
// same involution so swizzled reads see the right data (both-sides rule).
__device__ __forceinline__ int swz128(int row, int colb) {
    return row * 128 + ((((colb >> 4) ^ (row & 7)) << 4) | (colb & 15));
}
__device__ __forceinline__ int swz256(int row, int colb) {
    return row * 256 + ((((colb >> 4) ^ (row & 7)) << 4) | (colb & 15));
}

// ---------------------------------------------------------------------------
// KT: x [B][CIN][N] f32  ->  xT [B][N][CIN] bf16   (LDS 64x64 tile transpose)
// ---------------------------------------------------------------------------
__global__ __launch_bounds__(256) void kt_transpose(const float* __restrict__ x,
                                                    bf16* __restrict__ xT) {
    __shared__ float tile[64][65];
    int n0 = blockIdx.x * 64, c0 = blockIdx.y * 64, b = blockIdx.z;
    const float* xp = x + (size_t)b * CIN * NPOS;
    int t = threadIdx.x;
    int lr = t >> 4;            // 0..15
    int lc4 = (t & 15) * 4;     // 0..60
    for (int p = 0; p < 4; ++p) {
        int c = lr + p * 16;
        f32x4 v = *reinterpret_cast<const f32x4*>(xp + (size_t)(c0 + c) * NPOS + n0 + lc4);
        tile[c][lc4 + 0] = v[0]; tile[c][lc4 + 1] = v[1];
        tile[c][lc4 + 2] = v[2]; tile[c][lc4 + 3] = v[3];
    }
    __syncthreads();
    bf16* xtp = xT + (size_t)b * NPOS * CIN;
    int cc = (t & 15) * 4;
    for (int p = 0; p < 4; ++p) {
        int n = (t >> 4) + p * 16;
        bf16x4 o;
        o[0] = (bf16)tile[cc + 0][n]; o[1] = (bf16)tile[cc + 1][n];
        o[2] = (bf16)tile[cc + 2][n]; o[3] = (bf16)tile[cc + 3][n];
        *reinterpret_cast<bf16x4*>(xtp + (size_t)(n0 + n) * CIN + c0 + cc) = o;
    }
}

// ---------------------------------------------------------------------------
// K1: q/k/v = W @ x + b.  grid (32 ntile, 3 which, B).
// Output: qT,kT [B][N][128] bf16 (pos-major), vC [B][128][N] bf16 (ch-major).
// ---------------------------------------------------------------------------
__global__ __launch_bounds__(256) void k_qkv(
    const float* __restrict__ Wq, const float* __restrict__ Wk, const float* __restrict__ Wv,
    const float* __restrict__ bq, const float* __restrict__ bk, const float* __restrict__ bv,
    const bf16* __restrict__ xT, bf16* __restrict__ qT, bf16* __restrict__ kT,
    bf16* __restrict__ vC) {
    __shared__ __align__(16) char a_lds[128 * 128];  // [128 o][64 k] bf16 swz
    __shared__ __align__(16) char b_lds[128 * 128];  // [128 n][64 k] bf16 swz
    int n0 = blockIdx.x * 128, which = blockIdx.y, b = blockIdx.z;
    const float* W    = which == 0 ? Wq : (which == 1 ? Wk : Wv);
    const float* bias = which == 0 ? bq : (which == 1 ? bk : bv);
    int t = threadIdx.x, lane = t & 63, w = t >> 6, wy = w >> 1, wx = w & 1;
    const bf16* xb = xT + (size_t)b * NPOS * CIN;

    f32x4 acc[4][4] = {};
    for (int k0 = 0; k0 < 256; k0 += 64) {
        __syncthreads();
        for (int i = 0; i < 8; ++i) {                 // A: W f32 -> bf16
            int idx = t + i * 256;                    // 2048 float4
            int row = idx >> 4, c4 = (idx & 15) * 4;
            f32x4 v = *reinterpret_cast<const f32x4*>(W + (size_t)row * CIN + k0 + c4);
            bf16x4 o; o[0] = (bf16)v[0]; o[1] = (bf16)v[1]; o[2] = (bf16)v[2]; o[3] = (bf16)v[3];
            *reinterpret_cast<bf16x4*>(a_lds + swz128(row, c4 * 2)) = o;
        }
        for (int i = 0; i < 4; ++i) {                 // B: xT bf16 copy
            int idx = t + i * 256;                    // 1024 16B chunks
            int row = idx >> 3, cb = (idx & 7) * 16;
            bf16x8 vv = *reinterpret_cast<const bf16x8*>(xb + (size_t)(n0 + row) * CIN + k0 + cb / 2);
            *reinterpret_cast<bf16x8*>(b_lds + swz128(row, cb)) = vv;
        }
        __syncthreads();
        for (int ks = 0; ks < 2; ++ks) {
            int kb = ks * 64 + (lane >> 4) * 16;
            bf16x8 af[4], bfr[4];
            for (int i = 0; i < 4; ++i)
                af[i] = *reinterpret_cast<const bf16x8*>(a_lds + swz128(wy * 64 + i * 16 + (lane & 15), kb));
            for (int j = 0; j < 4; ++j)
                bfr[j] = *reinterpret_cast<const bf16x8*>(b_lds + swz128(wx * 64 + j * 16 + (lane & 15), kb));
            for (int i = 0; i < 4; ++i)
                for (int j = 0; j < 4; ++j)
                    acc[i][j] = MFMA16(af[i], bfr[j], acc[i][j]);
        }
    }
    int rg = lane >> 4, cl = lane & 15;
    for (int i = 0; i < 4; ++i) {
        int ch0 = wy * 64 + i * 16 + rg * 4;
        f32x4 bv4 = *reinterpret_cast<const f32x4*>(bias + ch0);
        for (int j = 0; j < 4; ++j) {
            int n = n0 + wx * 64 + j * 16 + cl;
            f32x4 d = acc[i][j];
            for (int r = 0; r < 4; ++r) d[r] += bv4[r];
            if (which == 2) {
                for (int r = 0; r < 4; ++r)
                    vC[((size_t)b * CMID + ch0 + r) * NPOS + n] = (bf16)d[r];
            } else {
                bf16x4 o; o[0] = (bf16)d[0]; o[1] = (bf16)d[1]; o[2] = (bf16)d[2]; o[3] = (bf16)d[3];
                bf16* dst = (which == 0 ? qT : kT);
                *reinterpret_cast<bf16x4*>(dst + ((size_t)b * NPOS + n) * CMID + ch0) = o;
            }
        }
    }
}

// ---------------------------------------------------------------------------
// K2: zpart[mq][b][n] = sum_{m in eighth mq} exp(S[n,m]), S[n,m]=k[:,n].q[:,m]
// grid (32 ntile, 8 mq, B). k-frags in registers; q staged via async DMA into
// double-buffered LDS, prefetch issued before compute, 1 barrier/step.
// ---------------------------------------------------------------------------
__global__ __launch_bounds__(256, 4) void k_zrow(const bf16* __restrict__ qT,
                                                 const bf16* __restrict__ kT,
                                                 float* __restrict__ zpart) {
    __shared__ __align__(16) char q_lds[2][64 * 256];  // [64 m][128 c] bf16 swz
    int n0 = blockIdx.x * 128, mq = blockIdx.y, b = blockIdx.z;
    int t = threadIdx.x, lane = t & 63, w = t >> 6;
    int cl = lane & 15, g = lane >> 4;
    const bf16* qb = qT + (size_t)b * NPOS * CMID;
    const bf16* kb = kT + (size_t)b * NPOS * CMID;

    auto stage_q = [&](int buf, int m0) {
        #pragma unroll
        for (int i = 0; i < 4; ++i) {
            int lc = (w * 4 + i) * 64 + lane;        // 16B-chunk idx in tile
            int r = lc >> 4, p = lc & 15;
            GLDS(qb + (size_t)(m0 + r) * CMID + ((p ^ (r & 7)) << 3),
                 q_lds[buf] + (w * 4 + i) * 1024);
        }
    };

    // k fragments (B-operand): wave owns n = n0 + w*32 + jn*16 + cl
    bf16x8 kreg[2][4];
    for (int jn = 0; jn < 2; ++jn)
        for (int ks = 0; ks < 4; ++ks)
            kreg[jn][ks] = *reinterpret_cast<const bf16x8*>(
                kb + (size_t)(n0 + w * 32 + jn * 16 + cl) * CMID + ks * 32 + g * 8);

    int mbeg = mq * (NPOS / 8);
    stage_q(0, mbeg);
    asm volatile("s_waitcnt vmcnt(0)" ::: "memory");
    __syncthreads();
    int cur = 0;
    float zacc[2] = {0.f, 0.f};
    for (int m0 = mbeg; m0 < mbeg + NPOS / 8; m0 += 64) {
        if (m0 + 64 < mbeg + NPOS / 8) stage_q(cur ^ 1, m0 + 64);
        f32x4 acc[4][2] = {};   // D[m][n]: m-tiles im, n-tiles jn
        for (int ks = 0; ks < 4; ++ks) {
            bf16x8 qf[4];
            for (int im = 0; im < 4; ++im)
                qf[im] = *reinterpret_cast<const bf16x8*>(q_lds[cur] + swz256(im * 16 + cl, ks * 64 + g * 16));
            for (int im = 0; im < 4; ++im)
                for (int jn = 0; jn < 2; ++jn)
                    acc[im][jn] = MFMA16(qf[im], kreg[jn][ks], acc[im][jn]);
        }
        for (int im = 0; im < 4; ++im)
            for (int jn = 0; jn < 2; ++jn)
                for (int r = 0; r < 4; ++r)
                    zacc[jn] += __expf(acc[im][jn][r]);
        __syncthreads();        // drains lgkm (reads of cur) + vmcnt (buf cur^1)
        cur ^= 1;
    }
    for (int jn = 0; jn < 2; ++jn) {
        zacc[jn] += __shfl_xor(zacc[jn], 16);
        zacc[jn] += __shfl_xor(zacc[jn], 32);
    }
    if (g == 0) {
        float* zp = zpart + ((size_t)mq * BATCH + b) * NPOS;
        zp[n0 + w * 32 + cl]      = zacc[0];
        zp[n0 + w * 32 + 16 + cl] = zacc[1];
    }
}

// ---------------------------------------------------------------------------
// K3: invZ = 1 / sum_{s<8} zpart[s].   16384 elems, f32x4.
// ---------------------------------------------------------------------------
__global__ __launch_bounds__(256) void k_rcp(const float* __restrict__ zpart,
                                             float* __restrict__ invZ) {
    int i = (blockIdx.x * 256 + threadIdx.x) * 4;
    f32x4 s = {0.f, 0.f, 0.f, 0.f};
    for (int p = 0; p < 8; ++p) {
        f32x4 a = *reinterpret_cast<const f32x4*>(zpart + (size_t)p * BATCH * NPOS + i);
        for (int r = 0; r < 4; ++r) s[r] += a[r];
    }
    f32x4 o;
    for (int r = 0; r < 4; ++r) o[r] = 1.f / s[r];
    *reinterpret_cast<f32x4*>(invZ + i) = o;
}

// ---------------------------------------------------------------------------
// K3b: vC[c,n] *= invZ[n]  (in-place; vC is rebuilt by k_qkv every call).
// Folds the softmax normalizer into v so k_attn's P = raw exp(S).
// ---------------------------------------------------------------------------
__global__ __launch_bounds__(256) void k_vscale(bf16* __restrict__ vC,
                                                const float* __restrict__ invZ) {
    int idx = blockIdx.x * 256 + threadIdx.x;   // one bf16x8 chunk (8 n)
    int b = idx >> 16;                          // 65536 chunks per batch
    int n8 = idx & (NPOS / 8 - 1);
    bf16x8 v = *reinterpret_cast<const bf16x8*>(vC + (size_t)idx * 8);
    const float* iz = invZ + (size_t)b * NPOS + n8 * 8;
    f32x4 i0 = *reinterpret_cast<const f32x4*>(iz);
    f32x4 i1 = *reinterpret_cast<const f32x4*>(iz + 4);
    bf16x8 o;
    for (int r = 0; r < 4; ++r) {
        o[r]     = (bf16)((float)v[r]     * i0[r]);
        o[r + 4] = (bf16)((float)v[r + 4] * i1[r]);
    }
    *reinterpret_cast<bf16x8*>(vC + (size_t)idx * 8) = o;
}

// ---------------------------------------------------------------------------
// K4: y[m][c] = sum_n exp(S[n,m]) vs[c,n]  (vs = invZ-prescaled v).
// grid (32 mtile(128), 4 nq, B) = 512 blocks, 2/CU.  q-frags in registers;
// k/v staged via async DMA into double-buffered LDS.  PV splits by m, so each
// wave consumes ONLY its own P quarter -> NO mid-step barrier; waves free-run
// between staging barriers (1 barrier/step).
// ---------------------------------------------------------------------------
__global__ __launch_bounds__(256, 2) void k_attn(const bf16* __restrict__ qT,
                                                 const bf16* __restrict__ kT,
                                                 const bf16* __restrict__ vS,
                                                 bf16* __restrict__ ypA,
                                                 bf16* __restrict__ ypB) {
    __shared__ __align__(16) char k_lds[2][64 * 256];   // [64 n][128 c] swz256
    __shared__ __align__(16) char v_lds[2][128 * 128];  // [128 c][64 n] swz128
    __shared__ __align__(16) char p_lds[128 * 128];     // [128 m][64 n] swz128
    int m0 = blockIdx.x * 128, nq = blockIdx.y, b = blockIdx.z;
    int t = threadIdx.x, lane = t & 63, w = t >> 6;
    int cl = lane & 15, g = lane >> 4;
    const bf16* qb = qT + (size_t)b * NPOS * CMID;
    const bf16* kb = kT + (size_t)b * NPOS * CMID;
    const bf16* vb = vS + (size_t)b * CMID * NPOS;

    auto stage_kv = [&](int buf, int n0) {
        #pragma unroll
        for (int i = 0; i < 4; ++i) {
            int lc = (w * 4 + i) * 64 + lane;        // 16B-chunk idx in tile
            int kr = lc >> 4, kp = lc & 15;          // k: 16 chunks per row
            GLDS(kb + (size_t)(n0 + kr) * CMID + ((kp ^ (kr & 7)) << 3),
                 k_lds[buf] + (w * 4 + i) * 1024);
            int vr = lc >> 3, vp = lc & 7;           // v: 8 chunks per row
            GLDS(vb + (size_t)vr * NPOS + n0 + ((vp ^ (vr & 7)) << 3),
                 v_lds[buf] + (w * 4 + i) * 1024);
        }
    };

    // q fragments (B-operand): wave owns m-cols m0 + w*32 + jm*16 + cl
    bf16x8 qreg[2][4];
    for (int jm = 0; jm < 2; ++jm)
        for (int ks = 0; ks < 4; ++ks)
            qreg[jm][ks] = *reinterpret_cast<const bf16x8*>(
                qb + (size_t)(m0 + w * 32 + jm * 16 + cl) * CMID + ks * 32 + g * 8);

    f32x4 acc2[2][8] = {};                           // y[m: wave's 32][c: 128]
    int nbeg = nq * (NPOS / 4);
    stage_kv(0, nbeg);
    asm volatile("s_waitcnt vmcnt(0)" ::: "memory");
    __syncthreads();
    int cur = 0;
    for (int s = 0; s < NPOS / 4 / 64; ++s) {
        int n0 = nbeg + s * 64;
        if (s + 1 < NPOS / 4 / 64) stage_kv(cur ^ 1, n0 + 64);
        // S^T: acc1[in][jm] = D[n=in*16+g*4+r][m = w*32+jm*16+cl]
        f32x4 acc1[4][2] = {};
        for (int ks = 0; ks < 4; ++ks) {
            bf16x8 kf[4];
            for (int in = 0; in < 4; ++in)
                kf[in] = *reinterpret_cast<const bf16x8*>(k_lds[cur] + swz256(in * 16 + cl, ks * 64 + g * 16));
            for (int in = 0; in < 4; ++in)
                for (int jm = 0; jm < 2; ++jm)
                    acc1[in][jm] = MFMA16(kf[in], qreg[jm][ks], acc1[in][jm]);
        }
        // P^T[m][n] = exp(S) raw (<= e^25, fits bf16); wave-private region.
        for (int in = 0; in < 4; ++in)
            for (int jm = 0; jm < 2; ++jm) {
                bf16x4 o;
                for (int r = 0; r < 4; ++r) o[r] = (bf16)__expf(acc1[in][jm][r]);
                *reinterpret_cast<bf16x4*>(p_lds + swz128(w * 32 + jm * 16 + cl, in * 32 + g * 8)) = o;
            }
        // PV, m-split: A = own P rows (m = w*32+jm*16+cl), B = vs tiles (c).
        // No barrier: only same-wave P is read (lgkmcnt ordering suffices).
        for (int s32 = 0; s32 < 2; ++s32) {
            bf16x8 af[2], vf[8];
            for (int jm = 0; jm < 2; ++jm)
                af[jm] = *reinterpret_cast<const bf16x8*>(p_lds + swz128(w * 32 + jm * 16 + cl, s32 * 64 + g * 16));
            for (int j = 0; j < 8; ++j)
                vf[j] = *reinterpret_cast<const bf16x8*>(v_lds[cur] + swz128(j * 16 + cl, s32 * 64 + g * 16));
            for (int jm = 0; jm < 2; ++jm)
                for (int j = 0; j < 8; ++j)
                    acc2[jm][j] = MFMA16(af[jm], vf[j], acc2[jm][j]);
        }
        __syncthreads();   // staged buf ready (vm drained) + reads of cur done
        cur ^= 1;
    }
    bf16* yb = ((nq & 2) ? ypB : ypA) + ((size_t)(nq & 1) * BATCH + b) * NPOS * CMID
             + (size_t)m0 * CMID;
    for (int jm = 0; jm < 2; ++jm)
        for (int j = 0; j < 8; ++j) {
            int c = j * 16 + cl;
            for (int r = 0; r < 4; ++r) {
                int m = w * 32 + jm * 16 + g * 4 + r;
                yb[(size_t)m * CMID + c] = (bf16)acc2[jm][j][r];
            }
        }
}

// ---------------------------------------------------------------------------
// K5: out = (Ww @ sum(y-slices) + bw)*inv + add + x. grid (32 mtile,2 otile,B).
// ---------------------------------------------------------------------------
__global__ __launch_bounds__(256) void k_out(
    const float* __restrict__ Ww, const float* __restrict__ bw,
    const float* __restrict__ gamma, const float* __restrict__ beta,
    const float* __restrict__ mean, const float* __restrict__ var,
    const bf16* __restrict__ ypA, const bf16* __restrict__ ypB,
    const float* __restrict__ x, float* __restrict__ out) {
    __shared__ __align__(16) char a_lds[128 * 128];  // [128 o][64 c] bf16 swz
    __shared__ __align__(16) char b_lds[128 * 128];  // [128 m][64 c] bf16 swz
    int m0 = blockIdx.x * 128, o0 = blockIdx.y * 128, b = blockIdx.z;
    int t = threadIdx.x, lane = t & 63, w = t >> 6, wy = w >> 1, wx = w & 1;
    size_t boff = (size_t)b * NPOS * CMID;
    const bf16* y0 = ypA + boff;
    const bf16* y1 = ypA + (size_t)BATCH * NPOS * CMID + boff;
    const bf16* y2 = ypB + boff;
    const bf16* y3 = ypB + (size_t)BATCH * NPOS * CMID + boff;
    f32x4 acc[4][4] = {};
    for (int k0 = 0; k0 < 128; k0 += 64) {
        __syncthreads();
        for (int i = 0; i < 8; ++i) {
            int idx = t + i * 256, row = idx >> 4, c4 = (idx & 15) * 4;
            f32x4 v = *reinterpret_cast<const f32x4*>(Ww + (size_t)(o0 + row) * CMID + k0 + c4);
            bf16x4 o; o[0] = (bf16)v[0]; o[1] = (bf16)v[1]; o[2] = (bf16)v[2]; o[3] = (bf16)v[3];
            *reinterpret_cast<bf16x4*>(a_lds + swz128(row, c4 * 2)) = o;
        }
        for (int i = 0; i < 8; ++i) {
            int idx = t + i * 256, row = idx >> 4, c4 = (idx & 15) * 4;
            size_t yoff = (size_t)(m0 + row) * CMID + k0 + c4;
            bf16x4 a0 = *reinterpret_cast<const bf16x4*>(y0 + yoff);
            bf16x4 a1 = *reinterpret_cast<const bf16x4*>(y1 + yoff);
            bf16x4 a2 = *reinterpret_cast<const bf16x4*>(y2 + yoff);
            bf16x4 a3 = *reinterpret_cast<const bf16x4*>(y3 + yoff);
            bf16x4 o;
            for (int r = 0; r < 4; ++r)
                o[r] = (bf16)((float)a0[r] + (float)a1[r] + (float)a2[r] + (float)a3[r]);
            *reinterpret_cast<bf16x4*>(b_lds + swz128(row, c4 * 2)) = o;
        }
        __syncthreads();
        for (int ks = 0; ks < 2; ++ks) {
            int kb = ks * 64 + (lane >> 4) * 16;
            bf16x8 af[4], bfr[4];
            for (int i = 0; i < 4; ++i)
                af[i] = *reinterpret_cast<const bf16x8*>(a_lds + swz128(wy * 64 + i * 16 + (lane & 15), kb));
            for (int j = 0; j < 4; ++j)
                bfr[j] = *reinterpret_cast<const bf16x8*>(b_lds + swz128(wx * 64 + j * 16 + (lane & 15), kb));
            for (int i = 0; i < 4; ++i)
                for (int j = 0; j < 4; ++j)
                    acc[i][j] = MFMA16(af[i], bfr[j], acc[i][j]);
        }
    }
    int rg = lane >> 4, cl = lane & 15;
    const float* xb = x + (size_t)b * CIN * NPOS;
    float* ob = out + (size_t)b * CIN * NPOS;
    for (int i = 0; i < 4; ++i) {
        int och0 = o0 + wy * 64 + i * 16 + rg * 4;
        f32x4 g  = *reinterpret_cast<const f32x4*>(gamma + och0);
        f32x4 be = *reinterpret_cast<const f32x4*>(beta + och0);
        f32x4 mu = *reinterpret_cast<const f32x4*>(mean + och0);
        f32x4 va = *reinterpret_cast<const f32x4*>(var + och0);
        f32x4 bb = *reinterpret_cast<const f32x4*>(bw + och0);
        float invv[4], addv[4];
        for (int r = 0; r < 4; ++r) {
            invv[r] = g[r] / sqrtf(va[r] + EPS);
            addv[r] = be[r] - mu[r] * invv[r];
        }
        for (int j = 0; j < 4; ++j) {
            int m = m0 + wx * 64 + j * 16 + cl;
            for (int r = 0; r < 4; ++r) {
                float z = (acc[i][j][r] + bb[r]) * invv[r] + addv[r];
                ob[(size_t)(och0 + r) * NPOS + m] = z + xb[(size_t)(och0 + r) * NPOS + m];
            }
        }
    }
}

// ---------------------------------------------------------------------------
extern "C" void kernel_launch(void* const* d_in, const int* in_sizes, int n_in,
                              void* d_out, int out_size, void* d_ws, size_t ws_size,
                              hipStream_t stream) {
    const float* x     = (const float*)d_in[0];
    const float* Wq    = (const float*)d_in[1];
    const float* bq    = (const float*)d_in[2];
    const float* Wk    = (const float*)d_in[3];
    const float* bk    = (const float*)d_in[4];
    const float* Wv    = (const float*)d_in[5];
    const float* bv    = (const float*)d_in[6];
    const float* Ww    = (const float*)d_in[7];
    const float* bw    = (const float*)d_in[8];
    const float* gamma = (const float*)d_in[9];
    const float* beta  = (const float*)d_in[10];
    const float* mean  = (const float*)d_in[11];
    const float* var   = (const float*)d_in[12];
    float* out = (float*)d_out;

    char* ws = (char*)d_ws;
    // Region A (8MB): xT during kt/k_qkv, then reused as ypA (2 bf16 y-slices).
    char* regionA = ws;                    ws += (size_t)BATCH * NPOS * CIN * 2;   // 8 MB
    bf16* qT = (bf16*)ws;                  ws += (size_t)BATCH * NPOS * CMID * 2;  // 4 MB
    bf16* kT = (bf16*)ws;                  ws += (size_t)BATCH * NPOS * CMID * 2;  // 4 MB
    bf16* vC = (bf16*)ws;                  ws += (size_t)BATCH * NPOS * CMID * 2;  // 4 MB
    bf16* ypB = (bf16*)ws;                 ws += (size_t)2 * BATCH * NPOS * CMID * 2; // 8 MB
    float* zpart = (float*)ws;             ws += (size_t)8 * BATCH * NPOS * 4;     // 512 KB
    float* invZ = (float*)ws;                                                     // 64 KB
    bf16* xT  = (bf16*)regionA;
    bf16* ypA = (bf16*)regionA;            // valid once k_qkv no longer needs xT

    kt_transpose<<<dim3(NPOS / 64, CIN / 64, BATCH), 256, 0, stream>>>(x, xT);
    k_qkv<<<dim3(NPOS / 128, 3, BATCH), 256, 0, stream>>>(Wq, Wk, Wv, bq, bk, bv, xT, qT, kT, vC);
    k_zrow<<<dim3(NPOS / 128, 8, BATCH), 256, 0, stream>>>(qT, kT, zpart);
    k_rcp<<<dim3(BATCH * NPOS / 1024), 256, 0, stream>>>(zpart, invZ);
    k_vscale<<<dim3(BATCH * CMID * NPOS / 8 / 256), 256, 0, stream>>>(vC, invZ);
    k_attn<<<dim3(NPOS / 128, 4, BATCH), 256, 0, stream>>>(qT, kT, vC, ypA, ypB);
    k_out<<<dim3(NPOS / 128, 2, BATCH), 256, 0, stream>>>(Ww, bw, gamma, beta, mean, var, ypA, ypB, x, out);
}